// Round 5
// baseline (496.829 us; speedup 1.0000x reference)
//
#include <hip/hip_runtime.h>
#include <hip/hip_cooperative_groups.h>

namespace cg = cooperative_groups;

// Problem constants
#define NNODES  50000
#define D       128
#define E       32
#define NMP     3
#define DEG     32
#define NEDGE   200000
#define B       1024
#define NC      8
#define S       16

#define RPM      17408   // rows per mp in L0 row space (16384 level-1 + 1024 level-0)
#define NKT      9       // K tiles of 32 (K=288)
#define WSTRIDE  36864   // ushorts per (mp,lay) feat-weight block: 9*4*128*8
#define WESTRIDE 9216    // ushorts per mp edge-weight block: 9*4*32*8
#define NTILE    1088    // RPM/16 tiles per mp
#define GRID     768     // cooperative grid: 3 blocks/CU guaranteed co-resident

#define CONV_TASKS (1600000 + 6 * WSTRIDE + 3 * WESTRIDE)   // 1,848,832
#define TOT_TASKS  (CONV_TASKS + 3 * RPM)                    // 1,901,056

typedef float f4 __attribute__((ext_vector_type(4)));
typedef short bh8 __attribute__((ext_vector_type(8)));   // 8 bf16 in 4 VGPRs
typedef unsigned int uv4 __attribute__((ext_vector_type(4)));
typedef unsigned int uv2 __attribute__((ext_vector_type(2)));
typedef int iv4 __attribute__((ext_vector_type(4)));
typedef int iv2 __attribute__((ext_vector_type(2)));

static __device__ __forceinline__ unsigned short f2bf(float f) {
    unsigned int u = __float_as_uint(f);
    u = u + 0x7FFFu + ((u >> 16) & 1u);   // RN-even
    return (unsigned short)(u >> 16);
}
static __device__ __forceinline__ float bf2f(unsigned short h) {
    return __uint_as_float(((unsigned int)h) << 16);
}

// ============================================================================
// Fully fused cooperative kernel: conv+sample | aggfeat | edge+L1 | finalize
// ============================================================================
__global__ __launch_bounds__(256, 3) void fused_k(
    const float* __restrict__ feats, const float* __restrict__ Ws,
    const float* __restrict__ Wn, const float* __restrict__ We,
    const int* __restrict__ ids, const int* __restrict__ adjn,
    const int* __restrict__ adje, const float* __restrict__ edge_emb,
    const float* __restrict__ attn, const float* __restrict__ fcw,
    const float* __restrict__ fcb,
    unsigned short* __restrict__ fb, unsigned short* __restrict__ WT0,
    unsigned short* __restrict__ WTe, int* __restrict__ gx,
    int* __restrict__ eid1, unsigned short* __restrict__ fout,
    float* __restrict__ femb, float* __restrict__ out)
{
    cg::grid_group grid = cg::this_grid();
    const int bid = blockIdx.x;
    const int tid = threadIdx.x;
    const int w = tid >> 6, l = tid & 63;
    const float inv = 1.0f / (float)S;

    __shared__ unsigned short Asm[16][136];   // aggfeat: self feats
    __shared__ unsigned short Nsm[16][168];   // aggfeat: nin rows
    __shared__ unsigned short As2[4][304];    // tail: [f0||f1mean||edge] rows

    // ---------------- phase 1: conversion + level-1 sampling ----------------
    for (int i = bid * 256 + tid; i < TOT_TASKS; i += GRID * 256) {
        if (i < 1600000) {                          // feats -> bf16
            float4 v = ((const float4*)feats)[i];
            unsigned int p0 = (unsigned int)f2bf(v.x) | ((unsigned int)f2bf(v.y) << 16);
            unsigned int p1 = (unsigned int)f2bf(v.z) | ((unsigned int)f2bf(v.w) << 16);
            ((uint2*)fb)[i] = make_uint2(p0, p1);
        } else if (i < 1600000 + 6 * WSTRIDE) {     // feat weights transpose
            int i2 = i - 1600000;
            int ml = i2 / WSTRIDE, e = i2 % WSTRIDE;
            int j = e & 7, t1 = e >> 3;
            int n = t1 & 127, t2 = t1 >> 7;
            int q = t2 & 3, kt = t2 >> 2;
            int k = kt * 32 + q * 8 + j;
            float v = (k < 128) ? Ws[((size_t)ml * 128 + k) * 128 + n]
                                : Wn[((size_t)ml * 160 + (k - 128)) * 128 + n];
            WT0[(size_t)ml * WSTRIDE + e] = f2bf(v);
        } else if (i < CONV_TASKS) {                // edge weights transpose
            int i3 = i - 1600000 - 6 * WSTRIDE;
            int mp = i3 / WESTRIDE, e = i3 % WESTRIDE;
            int j = e & 7, t1 = e >> 3;
            int n = t1 & 31, t2 = t1 >> 5;
            int q = t2 & 3, kt = t2 >> 2;
            int k = kt * 32 + q * 8 + j;
            float v = We[(((size_t)mp * 2) * 288 + k) * 32 + n];
            WTe[(size_t)mp * WESTRIDE + e] = f2bf(v);
        } else {                                    // sampling
            int i4 = i - CONV_TASKS;
            int mp = i4 / RPM, r = i4 % RPM;
            if (r < 16384) {
                int node = ids[r >> 4];
                gx[mp * RPM + r]     = adjn[((size_t)mp * NNODES + node) * DEG + (r & 15)];
                eid1[mp * 16384 + r] = adje[((size_t)mp * NNODES + node) * DEG + (r & 15)];
            } else {
                gx[mp * RPM + r] = ids[r - 16384];
            }
        }
    }
    grid.sync();

    // ---------------- phase 2: gather-mean + layer-0 GEMM (58us body) -------
    {
        const int g = l >> 4, c = l & 15;
        const int d8 = l & 7;
        const unsigned int* fb32 = (const unsigned int*)fb;
        const int q = l >> 4, lm = l & 15;

        for (int t = bid; t < NMP * NTILE; t += GRID) {
            const int mp = t / NTILE, bx = t - mp * NTILE;
            const int r0 = bx * 16;
            const float* ee = edge_emb + (size_t)mp * NEDGE * E;

            iv4 srcv = *(const iv4*)(gx + mp * RPM + r0 + w * 4);

            iv4 nIdx[4]; iv2 eIdx[4]; unsigned int selfu[4];
#pragma unroll
            for (int rr = 0; rr < 4; ++rr) {
                const int src = srcv[rr];
                nIdx[rr]  = *(const iv4*)(adjn + ((size_t)mp * NNODES + src) * DEG + 4 * g);
                eIdx[rr]  = *(const iv2*)(adje + ((size_t)mp * NNODES + src) * DEG + 2 * (l >> 3));
                selfu[rr] = fb32[(size_t)src * 64 + l];
            }

            uv4 gN[4][4];
            f4  gE[4][2];
#pragma unroll
            for (int rr = 0; rr < 4; ++rr) {
#pragma unroll
                for (int p = 0; p < 4; ++p)
                    gN[rr][p] = *(const uv4*)(fb32 + (size_t)nIdx[rr][p] * 64 + c * 4);
                gE[rr][0] = *(const f4*)(ee + (size_t)eIdx[rr][0] * E + d8 * 4);
                gE[rr][1] = *(const f4*)(ee + (size_t)eIdx[rr][1] * E + d8 * 4);
            }
            asm volatile("" ::: "memory");   // no load sinks past here

#pragma unroll
            for (int rr = 0; rr < 4; ++rr) {
                const int lr = w * 4 + rr;
                float acc[8];
#pragma unroll
                for (int d = 0; d < 8; ++d) acc[d] = 0.f;
#pragma unroll
                for (int p = 0; p < 4; ++p)
#pragma unroll
                    for (int qq = 0; qq < 4; ++qq) {
                        unsigned int u = gN[rr][p][qq];
                        acc[2 * qq]     += __uint_as_float(u << 16);
                        acc[2 * qq + 1] += __uint_as_float(u & 0xffff0000u);
                    }
#pragma unroll
                for (int d = 0; d < 8; ++d) {
                    acc[d] += __shfl_xor(acc[d], 16);
                    acc[d] += __shfl_xor(acc[d], 32);
                }
                float fe[4];
#pragma unroll
                for (int qq = 0; qq < 4; ++qq) {
                    fe[qq] = gE[rr][0][qq] + gE[rr][1][qq];
                    fe[qq] += __shfl_xor(fe[qq], 8);
                    fe[qq] += __shfl_xor(fe[qq], 16);
                    fe[qq] += __shfl_xor(fe[qq], 32);
                }

                ((unsigned int*)&Asm[lr][0])[l] = selfu[rr];
                if (g == 0) {
                    uv4 o;
#pragma unroll
                    for (int qq = 0; qq < 4; ++qq)
                        o[qq] = (unsigned int)f2bf(acc[2 * qq] * inv)
                              | ((unsigned int)f2bf(acc[2 * qq + 1] * inv) << 16);
                    *(uv4*)&Nsm[lr][c * 8] = o;
                }
                if (l < 8) {
                    uv2 o;
                    o[0] = (unsigned int)f2bf(fe[0] * inv) | ((unsigned int)f2bf(fe[1] * inv) << 16);
                    o[1] = (unsigned int)f2bf(fe[2] * inv) | ((unsigned int)f2bf(fe[3] * inv) << 16);
                    *(uv2*)&Nsm[lr][128 + d8 * 4] = o;
                }
            }
            __syncthreads();

            // GEMM: wave w -> n-tiles {2w, 2w+1}
            const unsigned short* wb = WT0 + (size_t)mp * 2 * WSTRIDE;
            f4 acc[2];
            acc[0] = (f4){0.f, 0.f, 0.f, 0.f};
            acc[1] = (f4){0.f, 0.f, 0.f, 0.f};
#pragma unroll
            for (int kt = 0; kt < NKT; ++kt) {
                const int k0 = kt * 32 + q * 8;
                bh8 a = (k0 < 128) ? *(const bh8*)&Asm[lm][k0]
                                   : *(const bh8*)&Nsm[lm][k0 - 128];
                const unsigned short* wrow = wb + ((size_t)(kt * 4 + q) * 128 + lm) * 8;
#pragma unroll
                for (int ntl = 0; ntl < 2; ++ntl) {
                    bh8 bf = *(const bh8*)(wrow + (w * 2 + ntl) * 16 * 8);
                    acc[ntl] = __builtin_amdgcn_mfma_f32_16x16x32_bf16(a, bf, acc[ntl], 0, 0, 0);
                }
            }
#pragma unroll
            for (int ntl = 0; ntl < 2; ++ntl)
#pragma unroll
                for (int rr = 0; rr < 4; ++rr) {
                    int row = r0 + q * 4 + rr;
                    int col = (w * 2 + ntl) * 16 + lm;
                    fout[((size_t)mp * RPM + row) * 128 + col] = f2bf(fmaxf(acc[ntl][rr], 0.f));
                }
            __syncthreads();   // LDS reused next tile
        }
    }
    grid.sync();

    // ---------------- phase 3a: edge GEMM + L1 mean + L1 GEMM -> femb -------
    {
        const int q = l >> 4, lm = l & 15;
        const int mp = bid >> 8, sgrp = bid & 255;         // 768 = 3 x 256
        const int m0 = sgrp * 64 + w * 16;                 // wave: 1 segment
        const unsigned short* we = WTe + (size_t)mp * WESTRIDE;
        const unsigned short* f1base = fout + (size_t)mp * RPM * 128;
        const unsigned short* f0base = fout + ((size_t)mp * RPM + 16384) * 128;
        const float* ee = edge_emb + (size_t)mp * NEDGE * E;

        const int row = m0 + lm;
        const unsigned short* a1p = f1base + (size_t)row * 128;
        const unsigned short* a0p = f0base + (size_t)(row >> 4) * 128;
        const int eidL = eid1[mp * 16384 + row];

        f4 acc[2];
        acc[0] = (f4){0.f, 0.f, 0.f, 0.f};
        acc[1] = (f4){0.f, 0.f, 0.f, 0.f};

#pragma unroll
        for (int kt = 0; kt < NKT; ++kt) {
            const int k0 = kt * 32 + q * 8;
            bh8 a;
            if (kt < 4) {
                a = *(const bh8*)(a0p + k0);
            } else if (kt < 8) {
                a = *(const bh8*)(a1p + (k0 - 128));
            } else {
                const float* ep = ee + (size_t)eidL * E + q * 8;
                float4 v0 = *(const float4*)ep;
                float4 v1 = *(const float4*)(ep + 4);
                bh8 tv;
                tv[0] = (short)f2bf(v0.x); tv[1] = (short)f2bf(v0.y);
                tv[2] = (short)f2bf(v0.z); tv[3] = (short)f2bf(v0.w);
                tv[4] = (short)f2bf(v1.x); tv[5] = (short)f2bf(v1.y);
                tv[6] = (short)f2bf(v1.z); tv[7] = (short)f2bf(v1.w);
                a = tv;
            }
            const unsigned short* wrow = we + ((size_t)(kt * 4 + q) * 32 + lm) * 8;
            bh8 b0 = *(const bh8*)(wrow);
            bh8 b1 = *(const bh8*)(wrow + 16 * 8);
            acc[0] = __builtin_amdgcn_mfma_f32_16x16x32_bf16(a, b0, acc[0], 0, 0, 0);
            acc[1] = __builtin_amdgcn_mfma_f32_16x16x32_bf16(a, b1, acc[1], 0, 0, 0);
        }

        // edge part of agg1 row: mean over segment's 16 rows
#pragma unroll
        for (int nt = 0; nt < 2; ++nt) {
            float ps = 0.f;
#pragma unroll
            for (int rr = 0; rr < 4; ++rr) ps += fmaxf(acc[nt][rr], 0.f);
            ps += __shfl_xor(ps, 16);
            ps += __shfl_xor(ps, 32);
            if (l < 16)
                As2[w][256 + nt * 16 + lm] = f2bf(ps * inv);
        }

        // f0 row + f1 mean
        {
            const int seg = m0 >> 4;
            unsigned int f0u = ((const unsigned int*)a0p)[l];
            ((unsigned int*)&As2[w][0])[l] = f0u;

            const unsigned short* fr = f1base + (size_t)seg * 16 * 128;
            float s0 = 0.f, s1 = 0.f;
#pragma unroll
            for (int j = 0; j < S; ++j) {
                unsigned int u = ((const unsigned int*)(fr + j * 128))[l];
                s0 += bf2f((unsigned short)(u & 0xFFFF));
                s1 += bf2f((unsigned short)(u >> 16));
            }
            ((unsigned int*)&As2[w][0])[64 + l] =
                (unsigned int)f2bf(s0 * inv) | ((unsigned int)f2bf(s1 * inv) << 16);
        }
        __syncthreads();

        // L1 GEMM: 4 valid rows, 8 n-tiles over 4 waves
        const unsigned short* wb1 = WT0 + ((size_t)mp * 2 + 1) * WSTRIDE;
        f4 acc2[2];
        acc2[0] = (f4){0.f, 0.f, 0.f, 0.f};
        acc2[1] = (f4){0.f, 0.f, 0.f, 0.f};
#pragma unroll
        for (int kt = 0; kt < NKT; ++kt) {
            const int k0 = kt * 32 + q * 8;
            bh8 a;
            if (lm < 4) a = *(const bh8*)&As2[lm][k0];
            else        a = (bh8){0, 0, 0, 0, 0, 0, 0, 0};
            const unsigned short* wrow = wb1 + ((size_t)(kt * 4 + q) * 128 + lm) * 8;
#pragma unroll
            for (int ntl = 0; ntl < 2; ++ntl) {
                bh8 bf = *(const bh8*)(wrow + (w * 2 + ntl) * 16 * 8);
                acc2[ntl] = __builtin_amdgcn_mfma_f32_16x16x32_bf16(a, bf, acc2[ntl], 0, 0, 0);
            }
        }
        if (q == 0) {
#pragma unroll
            for (int ntl = 0; ntl < 2; ++ntl)
#pragma unroll
                for (int rr = 0; rr < 4; ++rr) {
                    int seg = sgrp * 4 + rr;
                    femb[((size_t)mp * B + seg) * 128 + (w * 2 + ntl) * 16 + lm] =
                        fmaxf(acc2[ntl][rr], 0.f);
                }
        }
    }
    grid.sync();

    // ---------------- phase 3b: attention + softmax + normalize + fc --------
    if (bid < 32) {
        const int row = bid * 32 + (tid >> 3);
        const int j = tid & 7;
        const int d0 = j * 16;

        float v[NMP][16];
#pragma unroll
        for (int mp = 0; mp < NMP; ++mp)
#pragma unroll
            for (int t = 0; t < 4; ++t)
                *(f4*)&v[mp][t * 4] =
                    *(const f4*)&femb[((size_t)mp * B + row) * 128 + d0 + t * 4];

        float sc[NMP];
#pragma unroll
        for (int mp = 0; mp < NMP; ++mp) {
            float p = 0.f;
#pragma unroll
            for (int d = 0; d < 16; ++d) p += v[mp][d] * attn[d0 + d];
            p += __shfl_xor(p, 1); p += __shfl_xor(p, 2); p += __shfl_xor(p, 4);
            sc[mp] = tanhf(p);
        }
        float mx = fmaxf(sc[0], fmaxf(sc[1], sc[2]));
        float e0 = expf(sc[0] - mx), e1 = expf(sc[1] - mx), e2 = expf(sc[2] - mx);
        float isum = 1.f / (e0 + e1 + e2);
        float b0 = e0 * isum, b1 = e1 * isum, b2 = e2 * isum;

        float emb[16];
        float nn = 0.f;
#pragma unroll
        for (int d = 0; d < 16; ++d) {
            float vv = b0 * v[0][d] + b1 * v[1][d] + b2 * v[2][d];
            emb[d] = vv;
            nn += vv * vv;
        }
        nn += __shfl_xor(nn, 1); nn += __shfl_xor(nn, 2); nn += __shfl_xor(nn, 4);
        float innorm = 1.f / fmaxf(sqrtf(nn), 1e-12f);
#pragma unroll
        for (int d = 0; d < 16; ++d) emb[d] *= innorm;

#pragma unroll
        for (int cc = 0; cc < NC; ++cc) {
            float p = 0.f;
#pragma unroll
            for (int d = 0; d < 16; ++d) p += emb[d] * fcw[(d0 + d) * NC + cc];
            p += __shfl_xor(p, 1); p += __shfl_xor(p, 2); p += __shfl_xor(p, 4);
            if (j == cc) out[(size_t)row * NC + cc] = p + fcb[cc];
        }
    }
}

// ============================================================================
// Fallback path (R4 kernels) — used only if cooperative launch fails
// ============================================================================
__global__ __launch_bounds__(256) void convsamp_k(
    const float* __restrict__ feats, const float* __restrict__ Ws,
    const float* __restrict__ Wn, const float* __restrict__ We,
    const int* __restrict__ ids, const int* __restrict__ adjn,
    const int* __restrict__ adje,
    unsigned short* __restrict__ fb, unsigned short* __restrict__ WT0,
    unsigned short* __restrict__ WTe, int* __restrict__ gx, int* __restrict__ eid1)
{
    int i = blockIdx.x * 256 + threadIdx.x;
    if (i < 1600000) {
        float4 v = ((const float4*)feats)[i];
        unsigned int p0 = (unsigned int)f2bf(v.x) | ((unsigned int)f2bf(v.y) << 16);
        unsigned int p1 = (unsigned int)f2bf(v.z) | ((unsigned int)f2bf(v.w) << 16);
        ((uint2*)fb)[i] = make_uint2(p0, p1);
    } else if (i < 1600000 + 6 * WSTRIDE) {
        int i2 = i - 1600000;
        int ml = i2 / WSTRIDE, e = i2 % WSTRIDE;
        int j = e & 7, t1 = e >> 3;
        int n = t1 & 127, t2 = t1 >> 7;
        int q = t2 & 3, kt = t2 >> 2;
        int k = kt * 32 + q * 8 + j;
        float v = (k < 128) ? Ws[((size_t)ml * 128 + k) * 128 + n]
                            : Wn[((size_t)ml * 160 + (k - 128)) * 128 + n];
        WT0[(size_t)ml * WSTRIDE + e] = f2bf(v);
    } else if (i < CONV_TASKS) {
        int i3 = i - 1600000 - 6 * WSTRIDE;
        int mp = i3 / WESTRIDE, e = i3 % WESTRIDE;
        int j = e & 7, t1 = e >> 3;
        int n = t1 & 31, t2 = t1 >> 5;
        int q = t2 & 3, kt = t2 >> 2;
        int k = kt * 32 + q * 8 + j;
        float v = We[(((size_t)mp * 2) * 288 + k) * 32 + n];
        WTe[(size_t)mp * WESTRIDE + e] = f2bf(v);
    } else if (i < TOT_TASKS) {
        int i4 = i - CONV_TASKS;
        int mp = i4 / RPM, r = i4 % RPM;
        if (r < 16384) {
            int node = ids[r >> 4];
            gx[mp * RPM + r]     = adjn[((size_t)mp * NNODES + node) * DEG + (r & 15)];
            eid1[mp * 16384 + r] = adje[((size_t)mp * NNODES + node) * DEG + (r & 15)];
        } else {
            gx[mp * RPM + r] = ids[r - 16384];
        }
    }
}

__global__ __launch_bounds__(256, 3) void aggfeat_k(
    const unsigned short* __restrict__ fb, const float* __restrict__ edge_emb,
    const int* __restrict__ adjn, const int* __restrict__ adje,
    const int* __restrict__ gx, const int* __restrict__ eid1,
    const unsigned short* __restrict__ WT0,
    unsigned short* __restrict__ fout)
{
    __shared__ unsigned short Asm[16][136];
    __shared__ unsigned short Nsm[16][168];
    const int mp = blockIdx.y;
    const int w = threadIdx.x >> 6, l = threadIdx.x & 63;
    const int r0 = blockIdx.x * 16;
    const unsigned int* fb32 = (const unsigned int*)fb;
    const float* ee = edge_emb + (size_t)mp * NEDGE * E;
    const float inv = 1.0f / (float)S;
    const int g = l >> 4, c = l & 15;
    const int d8 = l & 7;

    iv4 srcv = *(const iv4*)(gx + mp * RPM + r0 + w * 4);

    iv4 nIdx[4]; iv2 eIdx[4]; unsigned int selfu[4];
#pragma unroll
    for (int rr = 0; rr < 4; ++rr) {
        const int src = srcv[rr];
        nIdx[rr]  = *(const iv4*)(adjn + ((size_t)mp * NNODES + src) * DEG + 4 * g);
        eIdx[rr]  = *(const iv2*)(adje + ((size_t)mp * NNODES + src) * DEG + 2 * (l >> 3));
        selfu[rr] = fb32[(size_t)src * 64 + l];
    }

    uv4 gN[4][4];
    f4  gE[4][2];
#pragma unroll
    for (int rr = 0; rr < 4; ++rr) {
#pragma unroll
        for (int p = 0; p < 4; ++p)
            gN[rr][p] = *(const uv4*)(fb32 + (size_t)nIdx[rr][p] * 64 + c * 4);
        gE[rr][0] = *(const f4*)(ee + (size_t)eIdx[rr][0] * E + d8 * 4);
        gE[rr][1] = *(const f4*)(ee + (size_t)eIdx[rr][1] * E + d8 * 4);
    }
    asm volatile("" ::: "memory");

#pragma unroll
    for (int rr = 0; rr < 4; ++rr) {
        const int lr = w * 4 + rr;
        float acc[8];
#pragma unroll
        for (int d = 0; d < 8; ++d) acc[d] = 0.f;
#pragma unroll
        for (int p = 0; p < 4; ++p)
#pragma unroll
            for (int qq = 0; qq < 4; ++qq) {
                unsigned int u = gN[rr][p][qq];
                acc[2 * qq]     += __uint_as_float(u << 16);
                acc[2 * qq + 1] += __uint_as_float(u & 0xffff0000u);
            }
#pragma unroll
        for (int d = 0; d < 8; ++d) {
            acc[d] += __shfl_xor(acc[d], 16);
            acc[d] += __shfl_xor(acc[d], 32);
        }
        float fe[4];
#pragma unroll
        for (int qq = 0; qq < 4; ++qq) {
            fe[qq] = gE[rr][0][qq] + gE[rr][1][qq];
            fe[qq] += __shfl_xor(fe[qq], 8);
            fe[qq] += __shfl_xor(fe[qq], 16);
            fe[qq] += __shfl_xor(fe[qq], 32);
        }

        ((unsigned int*)&Asm[lr][0])[l] = selfu[rr];
        if (g == 0) {
            uv4 o;
#pragma unroll
            for (int qq = 0; qq < 4; ++qq)
                o[qq] = (unsigned int)f2bf(acc[2 * qq] * inv)
                      | ((unsigned int)f2bf(acc[2 * qq + 1] * inv) << 16);
            *(uv4*)&Nsm[lr][c * 8] = o;
        }
        if (l < 8) {
            uv2 o;
            o[0] = (unsigned int)f2bf(fe[0] * inv) | ((unsigned int)f2bf(fe[1] * inv) << 16);
            o[1] = (unsigned int)f2bf(fe[2] * inv) | ((unsigned int)f2bf(fe[3] * inv) << 16);
            *(uv2*)&Nsm[lr][128 + d8 * 4] = o;
        }
    }
    __syncthreads();

    const int q = l >> 4, lm = l & 15;
    const unsigned short* wb = WT0 + (size_t)mp * 2 * WSTRIDE;

    f4 acc[2];
    acc[0] = (f4){0.f, 0.f, 0.f, 0.f};
    acc[1] = (f4){0.f, 0.f, 0.f, 0.f};

#pragma unroll
    for (int kt = 0; kt < NKT; ++kt) {
        const int k0 = kt * 32 + q * 8;
        bh8 a = (k0 < 128) ? *(const bh8*)&Asm[lm][k0]
                           : *(const bh8*)&Nsm[lm][k0 - 128];
        const unsigned short* wrow = wb + ((size_t)(kt * 4 + q) * 128 + lm) * 8;
#pragma unroll
        for (int ntl = 0; ntl < 2; ++ntl) {
            bh8 bf = *(const bh8*)(wrow + (w * 2 + ntl) * 16 * 8);
            acc[ntl] = __builtin_amdgcn_mfma_f32_16x16x32_bf16(a, bf, acc[ntl], 0, 0, 0);
        }
    }

#pragma unroll
    for (int ntl = 0; ntl < 2; ++ntl)
#pragma unroll
        for (int rr = 0; rr < 4; ++rr) {
            int row = r0 + q * 4 + rr;
            int col = (w * 2 + ntl) * 16 + lm;
            fout[((size_t)mp * RPM + row) * 128 + col] = f2bf(fmaxf(acc[ntl][rr], 0.f));
        }
}

__global__ __launch_bounds__(256) void edgeaggfin_k(
    const unsigned short* __restrict__ fout, const float* __restrict__ edge_emb,
    const int* __restrict__ eid1, const unsigned short* __restrict__ WTe,
    const unsigned short* __restrict__ WT0,
    const float* __restrict__ attn, const float* __restrict__ fcw,
    const float* __restrict__ fcb, float* __restrict__ out)
{
    __shared__ unsigned short As2[4][304];
    __shared__ float fembs[NMP][4][128];
    const int w = threadIdx.x >> 6, l = threadIdx.x & 63;
    const int q = l >> 4, lm = l & 15;
    const float inv = 1.0f / (float)S;

    for (int mp = 0; mp < NMP; ++mp) {
        const int m0 = (blockIdx.x * 4 + w) * 16;
        const unsigned short* we = WTe + (size_t)mp * WESTRIDE;
        const unsigned short* f1base = fout + (size_t)mp * RPM * 128;
        const unsigned short* f0base = fout + ((size_t)mp * RPM + 16384) * 128;
        const float* ee = edge_emb + (size_t)mp * NEDGE * E;

        const int row = m0 + lm;
        const unsigned short* a1p = f1base + (size_t)row * 128;
        const unsigned short* a0p = f0base + (size_t)(row >> 4) * 128;
        const int eidL = eid1[mp * 16384 + row];

        f4 acc[2];
        acc[0] = (f4){0.f, 0.f, 0.f, 0.f};
        acc[1] = (f4){0.f, 0.f, 0.f, 0.f};

#pragma unroll
        for (int kt = 0; kt < NKT; ++kt) {
            const int k0 = kt * 32 + q * 8;
            bh8 a;
            if (kt < 4) {
                a = *(const bh8*)(a0p + k0);
            } else if (kt < 8) {
                a = *(const bh8*)(a1p + (k0 - 128));
            } else {
                const float* ep = ee + (size_t)eidL * E + q * 8;
                float4 v0 = *(const float4*)ep;
                float4 v1 = *(const float4*)(ep + 4);
                bh8 tv;
                tv[0] = (short)f2bf(v0.x); tv[1] = (short)f2bf(v0.y);
                tv[2] = (short)f2bf(v0.z); tv[3] = (short)f2bf(v0.w);
                tv[4] = (short)f2bf(v1.x); tv[5] = (short)f2bf(v1.y);
                tv[6] = (short)f2bf(v1.z); tv[7] = (short)f2bf(v1.w);
                a = tv;
            }
            const unsigned short* wrow = we + ((size_t)(kt * 4 + q) * 32 + lm) * 8;
            bh8 b0 = *(const bh8*)(wrow);
            bh8 b1 = *(const bh8*)(wrow + 16 * 8);
            acc[0] = __builtin_amdgcn_mfma_f32_16x16x32_bf16(a, b0, acc[0], 0, 0, 0);
            acc[1] = __builtin_amdgcn_mfma_f32_16x16x32_bf16(a, b1, acc[1], 0, 0, 0);
        }

#pragma unroll
        for (int nt = 0; nt < 2; ++nt) {
            float ps = 0.f;
#pragma unroll
            for (int rr = 0; rr < 4; ++rr) ps += fmaxf(acc[nt][rr], 0.f);
            ps += __shfl_xor(ps, 16);
            ps += __shfl_xor(ps, 32);
            if (l < 16)
                As2[w][256 + nt * 16 + lm] = f2bf(ps * inv);
        }

        {
            const int seg = m0 >> 4;
            unsigned int f0u = ((const unsigned int*)a0p)[l];
            ((unsigned int*)&As2[w][0])[l] = f0u;

            const unsigned short* fr = f1base + (size_t)seg * 16 * 128;
            float s0 = 0.f, s1 = 0.f;
#pragma unroll
            for (int j = 0; j < S; ++j) {
                unsigned int u = ((const unsigned int*)(fr + j * 128))[l];
                s0 += bf2f((unsigned short)(u & 0xFFFF));
                s1 += bf2f((unsigned short)(u >> 16));
            }
            ((unsigned int*)&As2[w][0])[64 + l] =
                (unsigned int)f2bf(s0 * inv) | ((unsigned int)f2bf(s1 * inv) << 16);
        }
        __syncthreads();

        const unsigned short* wb1 = WT0 + ((size_t)mp * 2 + 1) * WSTRIDE;
        f4 acc2[2];
        acc2[0] = (f4){0.f, 0.f, 0.f, 0.f};
        acc2[1] = (f4){0.f, 0.f, 0.f, 0.f};

#pragma unroll
        for (int kt = 0; kt < NKT; ++kt) {
            const int k0 = kt * 32 + q * 8;
            bh8 a;
            if (lm < 4) a = *(const bh8*)&As2[lm][k0];
            else        a = (bh8){0, 0, 0, 0, 0, 0, 0, 0};
            const unsigned short* wrow = wb1 + ((size_t)(kt * 4 + q) * 128 + lm) * 8;
#pragma unroll
            for (int ntl = 0; ntl < 2; ++ntl) {
                bh8 bf = *(const bh8*)(wrow + (w * 2 + ntl) * 16 * 8);
                acc2[ntl] = __builtin_amdgcn_mfma_f32_16x16x32_bf16(a, bf, acc2[ntl], 0, 0, 0);
            }
        }
        if (q == 0) {
#pragma unroll
            for (int ntl = 0; ntl < 2; ++ntl)
#pragma unroll
                for (int rr = 0; rr < 4; ++rr)
                    fembs[mp][rr][(w * 2 + ntl) * 16 + lm] = fmaxf(acc2[ntl][rr], 0.f);
        }
        __syncthreads();
    }

    if (threadIdx.x < 32) {
        const int row = threadIdx.x >> 3;
        const int j = threadIdx.x & 7;
        const int d0 = j * 16;

        float sc[NMP];
#pragma unroll
        for (int mp = 0; mp < NMP; ++mp) {
            float p = 0.f;
#pragma unroll
            for (int d = 0; d < 16; ++d) p += fembs[mp][row][d0 + d] * attn[d0 + d];
            p += __shfl_xor(p, 1); p += __shfl_xor(p, 2); p += __shfl_xor(p, 4);
            sc[mp] = tanhf(p);
        }
        float mx = fmaxf(sc[0], fmaxf(sc[1], sc[2]));
        float e0 = expf(sc[0] - mx), e1 = expf(sc[1] - mx), e2 = expf(sc[2] - mx);
        float isum = 1.f / (e0 + e1 + e2);
        float b0 = e0 * isum, b1 = e1 * isum, b2 = e2 * isum;

        float emb[16];
        float nn = 0.f;
#pragma unroll
        for (int d = 0; d < 16; ++d) {
            float vv = b0 * fembs[0][row][d0 + d] + b1 * fembs[1][row][d0 + d]
                     + b2 * fembs[2][row][d0 + d];
            emb[d] = vv;
            nn += vv * vv;
        }
        nn += __shfl_xor(nn, 1); nn += __shfl_xor(nn, 2); nn += __shfl_xor(nn, 4);
        float innorm = 1.f / fmaxf(sqrtf(nn), 1e-12f);
#pragma unroll
        for (int d = 0; d < 16; ++d) emb[d] *= innorm;

        const int grow = blockIdx.x * 4 + row;
#pragma unroll
        for (int cc = 0; cc < NC; ++cc) {
            float p = 0.f;
#pragma unroll
            for (int d = 0; d < 16; ++d) p += emb[d] * fcw[(d0 + d) * NC + cc];
            p += __shfl_xor(p, 1); p += __shfl_xor(p, 2); p += __shfl_xor(p, 4);
            if (j == cc) out[(size_t)grow * NC + cc] = p + fcb[cc];
        }
    }
}

extern "C" void kernel_launch(void* const* d_in, const int* in_sizes, int n_in,
                              void* d_out, int out_size, void* d_ws, size_t ws_size,
                              hipStream_t stream) {
    const int* ids        = (const int*)d_in[0];
    const float* feats    = (const float*)d_in[1];
    const float* edge_emb = (const float*)d_in[2];
    const int* adjn       = (const int*)d_in[3];
    const int* adje       = (const int*)d_in[4];
    const float* Ws       = (const float*)d_in[5];
    const float* Wn       = (const float*)d_in[6];
    const float* We       = (const float*)d_in[7];
    const float* attn     = (const float*)d_in[8];
    const float* fcw      = (const float*)d_in[9];
    const float* fcb      = (const float*)d_in[10];
    float* out = (float*)d_out;

    // workspace layout (~28.7 MB; all regions fully written before read each call)
    char* p = (char*)d_ws;
    unsigned short* WT0 = (unsigned short*)p; p += (size_t)6 * WSTRIDE * 2;
    unsigned short* WTe = (unsigned short*)p; p += (size_t)3 * WESTRIDE * 2;
    unsigned short* fb  = (unsigned short*)p; p += (size_t)NNODES * 128 * 2;
    int* gx   = (int*)p;                      p += (size_t)3 * RPM * 4;
    int* eid1 = (int*)p;                      p += (size_t)3 * 16384 * 4;
    unsigned short* fout = (unsigned short*)p; p += (size_t)3 * RPM * 128 * 2;
    float* femb = (float*)p;                   p += (size_t)3 * B * 128 * 4;

    void* args[] = {
        (void*)&feats, (void*)&Ws, (void*)&Wn, (void*)&We,
        (void*)&ids, (void*)&adjn, (void*)&adje, (void*)&edge_emb,
        (void*)&attn, (void*)&fcw, (void*)&fcb,
        (void*)&fb, (void*)&WT0, (void*)&WTe, (void*)&gx, (void*)&eid1,
        (void*)&fout, (void*)&femb, (void*)&out
    };
    hipError_t err = hipLaunchCooperativeKernel(
        (const void*)fused_k, dim3(GRID), dim3(256), args, 0, stream);
    if (err != hipSuccess) {
        (void)hipGetLastError();   // clear sticky error, fall back to 3-kernel path
        convsamp_k<<<TOT_TASKS / 256, 256, 0, stream>>>(feats, Ws, Wn, We, ids, adjn,
                                                        adje, fb, WT0, WTe, gx, eid1);
        aggfeat_k<<<dim3(NTILE, 3), 256, 0, stream>>>(fb, edge_emb, adjn, adje, gx,
                                                      eid1, WT0, fout);
        edgeaggfin_k<<<256, 256, 0, stream>>>(fout, edge_emb, eid1, WTe, WT0,
                                              attn, fcw, fcb, out);
    }
}

// Round 6
// 381.885 us; speedup vs baseline: 1.3010x; 1.3010x over previous
//
#include <hip/hip_runtime.h>

// Problem constants
#define NNODES  50000
#define D       128
#define E       32
#define NMP     3
#define DEG     32
#define NEDGE   200000
#define B       1024
#define NC      8
#define S       16

#define RPM      17408   // rows per mp in L0 row space (16384 level-1 + 1024 level-0)
#define NKT      9       // K tiles of 32 (K=288)
#define WSTRIDE  36864   // ushorts per (mp,lay) feat-weight block: 9*4*128*8
#define WESTRIDE 9216    // ushorts per mp edge-weight block: 9*4*32*8

#define CONV_TASKS (1600000 + 6 * WSTRIDE + 3 * WESTRIDE)   // 1,848,832
#define TOT_TASKS  (CONV_TASKS + 3 * RPM)                    // 1,901,056 = 7426*256

typedef float f4 __attribute__((ext_vector_type(4)));
typedef short bh8 __attribute__((ext_vector_type(8)));   // 8 bf16 in 4 VGPRs
typedef unsigned int uv4 __attribute__((ext_vector_type(4)));
typedef unsigned int uv2 __attribute__((ext_vector_type(2)));
typedef int iv4 __attribute__((ext_vector_type(4)));
typedef int iv2 __attribute__((ext_vector_type(2)));

static __device__ __forceinline__ unsigned short f2bf(float f) {
    unsigned int u = __float_as_uint(f);
    u = u + 0x7FFFu + ((u >> 16) & 1u);   // RN-even
    return (unsigned short)(u >> 16);
}
static __device__ __forceinline__ float bf2f(unsigned short h) {
    return __uint_as_float(((unsigned int)h) << 16);
}

// ---------- fused one-shot conversion + level-1 sampling ----------
// B-fragment order: dst[((kt*4+q)*N + n)*8 + j] = W[k = kt*32+q*8+j][n]
__global__ __launch_bounds__(256) void convsamp_k(
    const float* __restrict__ feats, const float* __restrict__ Ws,
    const float* __restrict__ Wn, const float* __restrict__ We,
    const int* __restrict__ ids, const int* __restrict__ adjn,
    const int* __restrict__ adje,
    unsigned short* __restrict__ fb, unsigned short* __restrict__ WT0,
    unsigned short* __restrict__ WTe, int* __restrict__ gx, int* __restrict__ eid1)
{
    int i = blockIdx.x * 256 + threadIdx.x;
    if (i < 1600000) {                          // feats: 50000*128/4 float4 tasks
        float4 v = ((const float4*)feats)[i];
        unsigned int p0 = (unsigned int)f2bf(v.x) | ((unsigned int)f2bf(v.y) << 16);
        unsigned int p1 = (unsigned int)f2bf(v.z) | ((unsigned int)f2bf(v.w) << 16);
        ((uint2*)fb)[i] = make_uint2(p0, p1);
    } else if (i < 1600000 + 6 * WSTRIDE) {     // feat weights: [mp][lay] K=288 (Ws||Wn), N=128
        int i2 = i - 1600000;
        int ml = i2 / WSTRIDE, e = i2 % WSTRIDE;
        int j = e & 7, t1 = e >> 3;
        int n = t1 & 127, t2 = t1 >> 7;
        int q = t2 & 3, kt = t2 >> 2;
        int k = kt * 32 + q * 8 + j;
        float v = (k < 128) ? Ws[((size_t)ml * 128 + k) * 128 + n]
                            : Wn[((size_t)ml * 160 + (k - 128)) * 128 + n];
        WT0[(size_t)ml * WSTRIDE + e] = f2bf(v);
    } else if (i < CONV_TASKS) {                // edge weights: [mp][lay0] K=288,N=32
        int i3 = i - 1600000 - 6 * WSTRIDE;
        int mp = i3 / WESTRIDE, e = i3 % WESTRIDE;
        int j = e & 7, t1 = e >> 3;
        int n = t1 & 31, t2 = t1 >> 5;
        int q = t2 & 3, kt = t2 >> 2;
        int k = kt * 32 + q * 8 + j;
        float v = We[(((size_t)mp * 2) * 288 + k) * 32 + n];
        WTe[(size_t)mp * WESTRIDE + e] = f2bf(v);
    } else if (i < TOT_TASKS) {                 // sampling: 3*RPM tasks
        int i4 = i - CONV_TASKS;
        int mp = i4 / RPM, r = i4 % RPM;
        if (r < 16384) {
            int node = ids[r >> 4];
            gx[mp * RPM + r]     = adjn[((size_t)mp * NNODES + node) * DEG + (r & 15)];
            eid1[mp * 16384 + r] = adje[((size_t)mp * NNODES + node) * DEG + (r & 15)];
        } else {
            gx[mp * RPM + r] = ids[r - 16384];
        }
    }
}

// ---------- fused gather-mean + layer-0 MFMA GEMM -> fout [mp][RPM][128] bf16 ----------
// R2 per-wave body (best measured) at 512 threads / 32 rows / 8 waves per block:
// same per-wave batch (24 gathers before the fence, VGPR 64) but 4 blocks/CU x
// 8 waves = 32 resident waves/CU vs 12 -> 2.7x in-flight gather ops (Little's
// law says prior per-wave restructurings were neutral because waves*loads was
// constant; this moves the other factor).
__global__ __launch_bounds__(512, 8) void aggfeat_k(
    const unsigned short* __restrict__ fb, const float* __restrict__ edge_emb,
    const int* __restrict__ adjn, const int* __restrict__ adje,
    const int* __restrict__ gx, const int* __restrict__ eid1,
    const unsigned short* __restrict__ WT0,
    unsigned short* __restrict__ fout)
{
    __shared__ unsigned short Asm[32][136];   // self feats (128 used)
    __shared__ unsigned short Nsm[32][168];   // nin rows (160 used)
    const int mp = blockIdx.y;
    const int w = threadIdx.x >> 6, l = threadIdx.x & 63;   // w in [0,8)
    const int r0 = blockIdx.x * 32;
    const unsigned int* fb32 = (const unsigned int*)fb;
    const float* ee = edge_emb + (size_t)mp * NEDGE * E;
    const float inv = 1.0f / (float)S;
    const int g = l >> 4, c = l & 15;         // neighbor gather: group g covers nbrs 4g..4g+3
    const int d8 = l & 7;                     // edge gather: 8 lanes per edge row

    // ---- phase A: wave w owns rows w*4 .. w*4+3 of the 32-row block ----
    iv4 srcv = *(const iv4*)(gx + mp * RPM + r0 + w * 4);

    iv4 nIdx[4]; iv2 eIdx[4]; unsigned int selfu[4];
#pragma unroll
    for (int rr = 0; rr < 4; ++rr) {
        const int src = srcv[rr];
        nIdx[rr]  = *(const iv4*)(adjn + ((size_t)mp * NNODES + src) * DEG + 4 * g);
        eIdx[rr]  = *(const iv2*)(adje + ((size_t)mp * NNODES + src) * DEG + 2 * (l >> 3));
        selfu[rr] = fb32[(size_t)src * 64 + l];
    }

    // issue ALL gathers for all 4 rows (24 VMEM, ~96 landing VGPRs)
    uv4 gN[4][4];
    f4  gE[4][2];
#pragma unroll
    for (int rr = 0; rr < 4; ++rr) {
#pragma unroll
        for (int p = 0; p < 4; ++p)
            gN[rr][p] = *(const uv4*)(fb32 + (size_t)nIdx[rr][p] * 64 + c * 4);
        gE[rr][0] = *(const f4*)(ee + (size_t)eIdx[rr][0] * E + d8 * 4);
        gE[rr][1] = *(const f4*)(ee + (size_t)eIdx[rr][1] * E + d8 * 4);
    }
    asm volatile("" ::: "memory");   // hard fence: no load may sink past here

#pragma unroll
    for (int rr = 0; rr < 4; ++rr) {
        const int lr = w * 4 + rr;
        float acc[8];
#pragma unroll
        for (int d = 0; d < 8; ++d) acc[d] = 0.f;
#pragma unroll
        for (int p = 0; p < 4; ++p)
#pragma unroll
            for (int qq = 0; qq < 4; ++qq) {
                unsigned int u = gN[rr][p][qq];
                acc[2 * qq]     += __uint_as_float(u << 16);
                acc[2 * qq + 1] += __uint_as_float(u & 0xffff0000u);
            }
#pragma unroll
        for (int d = 0; d < 8; ++d) {
            acc[d] += __shfl_xor(acc[d], 16);
            acc[d] += __shfl_xor(acc[d], 32);
        }
        float fe[4];
#pragma unroll
        for (int qq = 0; qq < 4; ++qq) {
            fe[qq] = gE[rr][0][qq] + gE[rr][1][qq];
            fe[qq] += __shfl_xor(fe[qq], 8);
            fe[qq] += __shfl_xor(fe[qq], 16);
            fe[qq] += __shfl_xor(fe[qq], 32);
        }

        ((unsigned int*)&Asm[lr][0])[l] = selfu[rr];
        if (g == 0) {
            uv4 o;
#pragma unroll
            for (int qq = 0; qq < 4; ++qq)
                o[qq] = (unsigned int)f2bf(acc[2 * qq] * inv)
                      | ((unsigned int)f2bf(acc[2 * qq + 1] * inv) << 16);
            *(uv4*)&Nsm[lr][c * 8] = o;
        }
        if (l < 8) {
            uv2 o;
            o[0] = (unsigned int)f2bf(fe[0] * inv) | ((unsigned int)f2bf(fe[1] * inv) << 16);
            o[1] = (unsigned int)f2bf(fe[2] * inv) | ((unsigned int)f2bf(fe[3] * inv) << 16);
            *(uv2*)&Nsm[lr][128 + d8 * 4] = o;
        }
    }
    __syncthreads();

    // ---- phase B: wave w -> m-tile (w>>2), n-tiles {2*(w&3), 2*(w&3)+1} ----
    const int q = l >> 4, lm = l & 15;
    const int mt = w >> 2, wq = w & 3;
    const unsigned short* wb = WT0 + (size_t)mp * 2 * WSTRIDE;   // layer 0

    f4 acc[2];
    acc[0] = (f4){0.f, 0.f, 0.f, 0.f};
    acc[1] = (f4){0.f, 0.f, 0.f, 0.f};

#pragma unroll
    for (int kt = 0; kt < NKT; ++kt) {
        const int k0 = kt * 32 + q * 8;
        bh8 a = (k0 < 128) ? *(const bh8*)&Asm[mt * 16 + lm][k0]
                           : *(const bh8*)&Nsm[mt * 16 + lm][k0 - 128];
        const unsigned short* wrow = wb + ((size_t)(kt * 4 + q) * 128 + lm) * 8;
#pragma unroll
        for (int ntl = 0; ntl < 2; ++ntl) {
            bh8 bf = *(const bh8*)(wrow + (wq * 2 + ntl) * 16 * 8);
            acc[ntl] = __builtin_amdgcn_mfma_f32_16x16x32_bf16(a, bf, acc[ntl], 0, 0, 0);
        }
    }

#pragma unroll
    for (int ntl = 0; ntl < 2; ++ntl)
#pragma unroll
        for (int rr = 0; rr < 4; ++rr) {
            int row = r0 + mt * 16 + q * 4 + rr;   // C/D: col=lane&15, row=quad*4+reg
            int col = (wq * 2 + ntl) * 16 + lm;
            fout[((size_t)mp * RPM + row) * 128 + col] = f2bf(fmaxf(acc[ntl][rr], 0.f));
        }
}

// ---------- fully fused tail: edge GEMM + L1 mean + L1 GEMM (all 3 mps)
//            + attention + softmax + normalize + fc -> out ----------
__global__ __launch_bounds__(256) void edgeaggfin_k(
    const unsigned short* __restrict__ fout, const float* __restrict__ edge_emb,
    const int* __restrict__ eid1, const unsigned short* __restrict__ WTe,
    const unsigned short* __restrict__ WT0,
    const float* __restrict__ attn, const float* __restrict__ fcw,
    const float* __restrict__ fcb, float* __restrict__ out)
{
    __shared__ unsigned short As2[4][304];      // 288 used; 608B rows (16B-aligned)
    __shared__ float fembs[NMP][4][128];        // relu(L1 GEMM) for this block's 4 rows
    const int w = threadIdx.x >> 6, l = threadIdx.x & 63;
    const int q = l >> 4, lm = l & 15;
    const float inv = 1.0f / (float)S;

    for (int mp = 0; mp < NMP; ++mp) {
        const int m0 = (blockIdx.x * 4 + w) * 16;          // wave: 1 m-tile = 1 segment
        const unsigned short* we = WTe + (size_t)mp * WESTRIDE;
        const unsigned short* f1base = fout + (size_t)mp * RPM * 128;
        const unsigned short* f0base = fout + ((size_t)mp * RPM + 16384) * 128;
        const float* ee = edge_emb + (size_t)mp * NEDGE * E;

        const int row = m0 + lm;
        const unsigned short* a1p = f1base + (size_t)row * 128;
        const unsigned short* a0p = f0base + (size_t)(row >> 4) * 128;
        const int eidL = eid1[mp * 16384 + row];

        f4 acc[2];
        acc[0] = (f4){0.f, 0.f, 0.f, 0.f};
        acc[1] = (f4){0.f, 0.f, 0.f, 0.f};

#pragma unroll
        for (int kt = 0; kt < NKT; ++kt) {
            const int k0 = kt * 32 + q * 8;
            bh8 a;
            if (kt < 4) {
                a = *(const bh8*)(a0p + k0);
            } else if (kt < 8) {
                a = *(const bh8*)(a1p + (k0 - 128));
            } else {
                const float* ep = ee + (size_t)eidL * E + q * 8;
                float4 v0 = *(const float4*)ep;
                float4 v1 = *(const float4*)(ep + 4);
                bh8 tv;
                tv[0] = (short)f2bf(v0.x); tv[1] = (short)f2bf(v0.y);
                tv[2] = (short)f2bf(v0.z); tv[3] = (short)f2bf(v0.w);
                tv[4] = (short)f2bf(v1.x); tv[5] = (short)f2bf(v1.y);
                tv[6] = (short)f2bf(v1.z); tv[7] = (short)f2bf(v1.w);
                a = tv;
            }
            const unsigned short* wrow = we + ((size_t)(kt * 4 + q) * 32 + lm) * 8;
            bh8 b0 = *(const bh8*)(wrow);
            bh8 b1 = *(const bh8*)(wrow + 16 * 8);
            acc[0] = __builtin_amdgcn_mfma_f32_16x16x32_bf16(a, b0, acc[0], 0, 0, 0);
            acc[1] = __builtin_amdgcn_mfma_f32_16x16x32_bf16(a, b1, acc[1], 0, 0, 0);
        }

        // edge part of agg1 row: mean over the 16 rows of this segment
#pragma unroll
        for (int nt = 0; nt < 2; ++nt) {
            float ps = 0.f;
#pragma unroll
            for (int rr = 0; rr < 4; ++rr) ps += fmaxf(acc[nt][rr], 0.f);
            ps += __shfl_xor(ps, 16);
            ps += __shfl_xor(ps, 32);               // sum over quads -> full column sum
            if (l < 16)
                As2[w][256 + nt * 16 + lm] = f2bf(ps * inv);
        }

        // f0 row (dims 2l, 2l+1) and f1 mean
        {
            const int seg = m0 >> 4;
            unsigned int f0u = ((const unsigned int*)a0p)[l];
            ((unsigned int*)&As2[w][0])[l] = f0u;

            const unsigned short* fr = f1base + (size_t)seg * 16 * 128;
            float s0 = 0.f, s1 = 0.f;
#pragma unroll
            for (int j = 0; j < S; ++j) {
                unsigned int u = ((const unsigned int*)(fr + j * 128))[l];
                s0 += bf2f((unsigned short)(u & 0xFFFF));
                s1 += bf2f((unsigned short)(u >> 16));
            }
            ((unsigned int*)&As2[w][0])[64 + l] =
                (unsigned int)f2bf(s0 * inv) | ((unsigned int)f2bf(s1 * inv) << 16);
        }
        __syncthreads();

        // ---- L1 GEMM: 4 valid rows, 8 n-tiles over 4 waves -> fembs[mp] ----
        const unsigned short* wb1 = WT0 + ((size_t)mp * 2 + 1) * WSTRIDE;
        f4 acc2[2];
        acc2[0] = (f4){0.f, 0.f, 0.f, 0.f};
        acc2[1] = (f4){0.f, 0.f, 0.f, 0.f};

#pragma unroll
        for (int kt = 0; kt < NKT; ++kt) {
            const int k0 = kt * 32 + q * 8;
            bh8 a;
            if (lm < 4) a = *(const bh8*)&As2[lm][k0];
            else        a = (bh8){0, 0, 0, 0, 0, 0, 0, 0};
            const unsigned short* wrow = wb1 + ((size_t)(kt * 4 + q) * 128 + lm) * 8;
#pragma unroll
            for (int ntl = 0; ntl < 2; ++ntl) {
                bh8 bf = *(const bh8*)(wrow + (w * 2 + ntl) * 16 * 8);
                acc2[ntl] = __builtin_amdgcn_mfma_f32_16x16x32_bf16(a, bf, acc2[ntl], 0, 0, 0);
            }
        }
        if (q == 0) {                               // rows 0-3 live in quad 0, reg rr
#pragma unroll
            for (int ntl = 0; ntl < 2; ++ntl)
#pragma unroll
                for (int rr = 0; rr < 4; ++rr)
                    fembs[mp][rr][(w * 2 + ntl) * 16 + lm] = fmaxf(acc2[ntl][rr], 0.f);
        }
        __syncthreads();                            // As2 reused next mp; fembs complete
    }

    // ---- finalize: 4 rows x 8 threads (threads 0..31), 16 dims each ----
    if (threadIdx.x < 32) {
        const int row = threadIdx.x >> 3;           // local row 0..3
        const int j = threadIdx.x & 7;
        const int d0 = j * 16;

        float sc[NMP];
#pragma unroll
        for (int mp = 0; mp < NMP; ++mp) {
            float p = 0.f;
#pragma unroll
            for (int d = 0; d < 16; ++d) p += fembs[mp][row][d0 + d] * attn[d0 + d];
            p += __shfl_xor(p, 1); p += __shfl_xor(p, 2); p += __shfl_xor(p, 4);
            sc[mp] = tanhf(p);
        }
        float mx = fmaxf(sc[0], fmaxf(sc[1], sc[2]));
        float e0 = expf(sc[0] - mx), e1 = expf(sc[1] - mx), e2 = expf(sc[2] - mx);
        float isum = 1.f / (e0 + e1 + e2);
        float b0 = e0 * isum, b1 = e1 * isum, b2 = e2 * isum;

        float emb[16];
        float nn = 0.f;
#pragma unroll
        for (int d = 0; d < 16; ++d) {
            float vv = b0 * fembs[0][row][d0 + d] + b1 * fembs[1][row][d0 + d]
                     + b2 * fembs[2][row][d0 + d];
            emb[d] = vv;
            nn += vv * vv;
        }
        nn += __shfl_xor(nn, 1); nn += __shfl_xor(nn, 2); nn += __shfl_xor(nn, 4);
        float innorm = 1.f / fmaxf(sqrtf(nn), 1e-12f);
#pragma unroll
        for (int d = 0; d < 16; ++d) emb[d] *= innorm;

        const int grow = blockIdx.x * 4 + row;
#pragma unroll
        for (int cc = 0; cc < NC; ++cc) {
            float p = 0.f;
#pragma unroll
            for (int d = 0; d < 16; ++d) p += emb[d] * fcw[(d0 + d) * NC + cc];
            p += __shfl_xor(p, 1); p += __shfl_xor(p, 2); p += __shfl_xor(p, 4);
            if (j == cc) out[(size_t)grow * NC + cc] = p + fcb[cc];
        }
    }
}

extern "C" void kernel_launch(void* const* d_in, const int* in_sizes, int n_in,
                              void* d_out, int out_size, void* d_ws, size_t ws_size,
                              hipStream_t stream) {
    const int* ids        = (const int*)d_in[0];
    const float* feats    = (const float*)d_in[1];
    const float* edge_emb = (const float*)d_in[2];
    const int* adjn       = (const int*)d_in[3];
    const int* adje       = (const int*)d_in[4];
    const float* Ws       = (const float*)d_in[5];
    const float* Wn       = (const float*)d_in[6];
    const float* We       = (const float*)d_in[7];
    const float* attn     = (const float*)d_in[8];
    const float* fcw      = (const float*)d_in[9];
    const float* fcb      = (const float*)d_in[10];
    float* out = (float*)d_out;

    // workspace layout (~27 MB; all regions fully written before read each call)
    char* p = (char*)d_ws;
    unsigned short* WT0 = (unsigned short*)p; p += (size_t)6 * WSTRIDE * 2;
    unsigned short* WTe = (unsigned short*)p; p += (size_t)3 * WESTRIDE * 2;
    unsigned short* fb  = (unsigned short*)p; p += (size_t)NNODES * 128 * 2;
    int* gx   = (int*)p;                      p += (size_t)3 * RPM * 4;
    int* eid1 = (int*)p;                      p += (size_t)3 * 16384 * 4;
    unsigned short* fout = (unsigned short*)p; p += (size_t)3 * RPM * 128 * 2;

    convsamp_k<<<TOT_TASKS / 256, 256, 0, stream>>>(feats, Ws, Wn, We, ids, adjn, adje,
                                                    fb, WT0, WTe, gx, eid1);
    aggfeat_k<<<dim3(RPM / 32, 3), 512, 0, stream>>>(fb, edge_emb, adjn, adje, gx, eid1,
                                                     WT0, fout);
    edgeaggfin_k<<<256, 256, 0, stream>>>(fout, edge_emb, eid1, WTe, WT0,
                                          attn, fcw, fcb, out);
}

// Round 7
// 229.385 us; speedup vs baseline: 2.1659x; 1.6648x over previous
//
#include <hip/hip_runtime.h>

// Problem constants
#define NNODES  50000
#define D       128
#define E       32
#define NMP     3
#define DEG     32
#define NEDGE   200000
#define B       1024
#define NC      8
#define S       16

#define RPM      17408   // rows per mp in L0 row space (16384 level-1 + 1024 level-0)
#define NKT      9       // K tiles of 32 (K=288)
#define WSTRIDE  36864   // ushorts per (mp,lay) feat-weight block: 9*4*128*8
#define WESTRIDE 9216    // ushorts per mp edge-weight block: 9*4*32*8

#define CONV_TASKS (1600000 + 6 * WSTRIDE + 3 * WESTRIDE)   // 1,848,832
#define TOT_TASKS  (CONV_TASKS + 3 * RPM)                    // 1,901,056 = 7426*256

typedef float f4 __attribute__((ext_vector_type(4)));
typedef short bh8 __attribute__((ext_vector_type(8)));   // 8 bf16 in 4 VGPRs
typedef unsigned int uv4 __attribute__((ext_vector_type(4)));
typedef unsigned int uv2 __attribute__((ext_vector_type(2)));
typedef int iv4 __attribute__((ext_vector_type(4)));
typedef int iv2 __attribute__((ext_vector_type(2)));

static __device__ __forceinline__ unsigned short f2bf(float f) {
    unsigned int u = __float_as_uint(f);
    u = u + 0x7FFFu + ((u >> 16) & 1u);   // RN-even
    return (unsigned short)(u >> 16);
}
static __device__ __forceinline__ float bf2f(unsigned short h) {
    return __uint_as_float(((unsigned int)h) << 16);
}

// ---------- fused one-shot conversion + level-1 sampling ----------
// B-fragment order: dst[((kt*4+q)*N + n)*8 + j] = W[k = kt*32+q*8+j][n]
__global__ __launch_bounds__(256) void convsamp_k(
    const float* __restrict__ feats, const float* __restrict__ Ws,
    const float* __restrict__ Wn, const float* __restrict__ We,
    const int* __restrict__ ids, const int* __restrict__ adjn,
    const int* __restrict__ adje,
    unsigned short* __restrict__ fb, unsigned short* __restrict__ WT0,
    unsigned short* __restrict__ WTe, int* __restrict__ gx, int* __restrict__ eid1)
{
    int i = blockIdx.x * 256 + threadIdx.x;
    if (i < 1600000) {                          // feats: 50000*128/4 float4 tasks
        float4 v = ((const float4*)feats)[i];
        unsigned int p0 = (unsigned int)f2bf(v.x) | ((unsigned int)f2bf(v.y) << 16);
        unsigned int p1 = (unsigned int)f2bf(v.z) | ((unsigned int)f2bf(v.w) << 16);
        ((uint2*)fb)[i] = make_uint2(p0, p1);
    } else if (i < 1600000 + 6 * WSTRIDE) {     // feat weights: [mp][lay] K=288 (Ws||Wn), N=128
        int i2 = i - 1600000;
        int ml = i2 / WSTRIDE, e = i2 % WSTRIDE;
        int j = e & 7, t1 = e >> 3;
        int n = t1 & 127, t2 = t1 >> 7;
        int q = t2 & 3, kt = t2 >> 2;
        int k = kt * 32 + q * 8 + j;
        float v = (k < 128) ? Ws[((size_t)ml * 128 + k) * 128 + n]
                            : Wn[((size_t)ml * 160 + (k - 128)) * 128 + n];
        WT0[(size_t)ml * WSTRIDE + e] = f2bf(v);
    } else if (i < CONV_TASKS) {                // edge weights: [mp][lay0] K=288,N=32
        int i3 = i - 1600000 - 6 * WSTRIDE;
        int mp = i3 / WESTRIDE, e = i3 % WESTRIDE;
        int j = e & 7, t1 = e >> 3;
        int n = t1 & 31, t2 = t1 >> 5;
        int q = t2 & 3, kt = t2 >> 2;
        int k = kt * 32 + q * 8 + j;
        float v = We[(((size_t)mp * 2) * 288 + k) * 32 + n];
        WTe[(size_t)mp * WESTRIDE + e] = f2bf(v);
    } else if (i < TOT_TASKS) {                 // sampling: 3*RPM tasks
        int i4 = i - CONV_TASKS;
        int mp = i4 / RPM, r = i4 % RPM;
        if (r < 16384) {
            int node = ids[r >> 4];
            gx[mp * RPM + r]     = adjn[((size_t)mp * NNODES + node) * DEG + (r & 15)];
            eid1[mp * 16384 + r] = adje[((size_t)mp * NNODES + node) * DEG + (r & 15)];
        } else {
            gx[mp * RPM + r] = ids[r - 16384];
        }
    }
}

// ---------- fused gather-mean + layer-0 MFMA GEMM -> fout [mp][RPM][128] bf16 ----------
// R6 geometry (512 thr / 32 rows / 8 waves: proved 77% residency) with the
// VGPR budget the batch actually needs: launch_bounds(512,4) caps at 128 VGPR
// (batch ~120), vs R6's (512,8) -> 32 VGPR which SPILLED the whole batch to
// scratch (WRITE_SIZE 13->398MB, dur 58->215us). R6 also proved the memory
// system sustains 3.6TB/s -- the 2.8TB/s plateau was concurrency-limited.
__global__ __launch_bounds__(512, 4) void aggfeat_k(
    const unsigned short* __restrict__ fb, const float* __restrict__ edge_emb,
    const int* __restrict__ adjn, const int* __restrict__ adje,
    const int* __restrict__ gx, const int* __restrict__ eid1,
    const unsigned short* __restrict__ WT0,
    unsigned short* __restrict__ fout)
{
    __shared__ unsigned short Asm[32][136];   // self feats (128 used)
    __shared__ unsigned short Nsm[32][168];   // nin rows (160 used)
    const int mp = blockIdx.y;
    const int w = threadIdx.x >> 6, l = threadIdx.x & 63;   // w in [0,8)
    const int r0 = blockIdx.x * 32;
    const unsigned int* fb32 = (const unsigned int*)fb;
    const float* ee = edge_emb + (size_t)mp * NEDGE * E;
    const float inv = 1.0f / (float)S;
    const int g = l >> 4, c = l & 15;         // neighbor gather: group g covers nbrs 4g..4g+3
    const int d8 = l & 7;                     // edge gather: 8 lanes per edge row

    // ---- phase A: wave w owns rows w*4 .. w*4+3 of the 32-row block ----
    iv4 srcv = *(const iv4*)(gx + mp * RPM + r0 + w * 4);

    iv4 nIdx[4]; iv2 eIdx[4]; unsigned int selfu[4];
#pragma unroll
    for (int rr = 0; rr < 4; ++rr) {
        const int src = srcv[rr];
        nIdx[rr]  = *(const iv4*)(adjn + ((size_t)mp * NNODES + src) * DEG + 4 * g);
        eIdx[rr]  = *(const iv2*)(adje + ((size_t)mp * NNODES + src) * DEG + 2 * (l >> 3));
        selfu[rr] = fb32[(size_t)src * 64 + l];
    }

    // issue ALL gathers for all 4 rows (24 VMEM, ~96 landing VGPRs)
    uv4 gN[4][4];
    f4  gE[4][2];
#pragma unroll
    for (int rr = 0; rr < 4; ++rr) {
#pragma unroll
        for (int p = 0; p < 4; ++p)
            gN[rr][p] = *(const uv4*)(fb32 + (size_t)nIdx[rr][p] * 64 + c * 4);
        gE[rr][0] = *(const f4*)(ee + (size_t)eIdx[rr][0] * E + d8 * 4);
        gE[rr][1] = *(const f4*)(ee + (size_t)eIdx[rr][1] * E + d8 * 4);
    }
    asm volatile("" ::: "memory");   // hard fence: no load may sink past here

#pragma unroll
    for (int rr = 0; rr < 4; ++rr) {
        const int lr = w * 4 + rr;
        float acc[8];
#pragma unroll
        for (int d = 0; d < 8; ++d) acc[d] = 0.f;
#pragma unroll
        for (int p = 0; p < 4; ++p)
#pragma unroll
            for (int qq = 0; qq < 4; ++qq) {
                unsigned int u = gN[rr][p][qq];
                acc[2 * qq]     += __uint_as_float(u << 16);
                acc[2 * qq + 1] += __uint_as_float(u & 0xffff0000u);
            }
#pragma unroll
        for (int d = 0; d < 8; ++d) {
            acc[d] += __shfl_xor(acc[d], 16);
            acc[d] += __shfl_xor(acc[d], 32);
        }
        float fe[4];
#pragma unroll
        for (int qq = 0; qq < 4; ++qq) {
            fe[qq] = gE[rr][0][qq] + gE[rr][1][qq];
            fe[qq] += __shfl_xor(fe[qq], 8);
            fe[qq] += __shfl_xor(fe[qq], 16);
            fe[qq] += __shfl_xor(fe[qq], 32);
        }

        ((unsigned int*)&Asm[lr][0])[l] = selfu[rr];
        if (g == 0) {
            uv4 o;
#pragma unroll
            for (int qq = 0; qq < 4; ++qq)
                o[qq] = (unsigned int)f2bf(acc[2 * qq] * inv)
                      | ((unsigned int)f2bf(acc[2 * qq + 1] * inv) << 16);
            *(uv4*)&Nsm[lr][c * 8] = o;
        }
        if (l < 8) {
            uv2 o;
            o[0] = (unsigned int)f2bf(fe[0] * inv) | ((unsigned int)f2bf(fe[1] * inv) << 16);
            o[1] = (unsigned int)f2bf(fe[2] * inv) | ((unsigned int)f2bf(fe[3] * inv) << 16);
            *(uv2*)&Nsm[lr][128 + d8 * 4] = o;
        }
    }
    __syncthreads();

    // ---- phase B: wave w -> m-tile (w>>2), n-tiles {2*(w&3), 2*(w&3)+1} ----
    const int q = l >> 4, lm = l & 15;
    const int mt = w >> 2, wq = w & 3;
    const unsigned short* wb = WT0 + (size_t)mp * 2 * WSTRIDE;   // layer 0

    f4 acc[2];
    acc[0] = (f4){0.f, 0.f, 0.f, 0.f};
    acc[1] = (f4){0.f, 0.f, 0.f, 0.f};

#pragma unroll
    for (int kt = 0; kt < NKT; ++kt) {
        const int k0 = kt * 32 + q * 8;
        bh8 a = (k0 < 128) ? *(const bh8*)&Asm[mt * 16 + lm][k0]
                           : *(const bh8*)&Nsm[mt * 16 + lm][k0 - 128];
        const unsigned short* wrow = wb + ((size_t)(kt * 4 + q) * 128 + lm) * 8;
#pragma unroll
        for (int ntl = 0; ntl < 2; ++ntl) {
            bh8 bf = *(const bh8*)(wrow + (wq * 2 + ntl) * 16 * 8);
            acc[ntl] = __builtin_amdgcn_mfma_f32_16x16x32_bf16(a, bf, acc[ntl], 0, 0, 0);
        }
    }

#pragma unroll
    for (int ntl = 0; ntl < 2; ++ntl)
#pragma unroll
        for (int rr = 0; rr < 4; ++rr) {
            int row = r0 + mt * 16 + q * 4 + rr;   // C/D: col=lane&15, row=quad*4+reg
            int col = (wq * 2 + ntl) * 16 + lm;
            fout[((size_t)mp * RPM + row) * 128 + col] = f2bf(fmaxf(acc[ntl][rr], 0.f));
        }
}

// ---------- fully fused tail: edge GEMM + L1 mean + L1 GEMM (all 3 mps)
//            + attention + softmax + normalize + fc -> out ----------
__global__ __launch_bounds__(256) void edgeaggfin_k(
    const unsigned short* __restrict__ fout, const float* __restrict__ edge_emb,
    const int* __restrict__ eid1, const unsigned short* __restrict__ WTe,
    const unsigned short* __restrict__ WT0,
    const float* __restrict__ attn, const float* __restrict__ fcw,
    const float* __restrict__ fcb, float* __restrict__ out)
{
    __shared__ unsigned short As2[4][304];      // 288 used; 608B rows (16B-aligned)
    __shared__ float fembs[NMP][4][128];        // relu(L1 GEMM) for this block's 4 rows
    const int w = threadIdx.x >> 6, l = threadIdx.x & 63;
    const int q = l >> 4, lm = l & 15;
    const float inv = 1.0f / (float)S;

    for (int mp = 0; mp < NMP; ++mp) {
        const int m0 = (blockIdx.x * 4 + w) * 16;          // wave: 1 m-tile = 1 segment
        const unsigned short* we = WTe + (size_t)mp * WESTRIDE;
        const unsigned short* f1base = fout + (size_t)mp * RPM * 128;
        const unsigned short* f0base = fout + ((size_t)mp * RPM + 16384) * 128;
        const float* ee = edge_emb + (size_t)mp * NEDGE * E;

        const int row = m0 + lm;
        const unsigned short* a1p = f1base + (size_t)row * 128;
        const unsigned short* a0p = f0base + (size_t)(row >> 4) * 128;
        const int eidL = eid1[mp * 16384 + row];

        f4 acc[2];
        acc[0] = (f4){0.f, 0.f, 0.f, 0.f};
        acc[1] = (f4){0.f, 0.f, 0.f, 0.f};

#pragma unroll
        for (int kt = 0; kt < NKT; ++kt) {
            const int k0 = kt * 32 + q * 8;
            bh8 a;
            if (kt < 4) {
                a = *(const bh8*)(a0p + k0);
            } else if (kt < 8) {
                a = *(const bh8*)(a1p + (k0 - 128));
            } else {
                const float* ep = ee + (size_t)eidL * E + q * 8;
                float4 v0 = *(const float4*)ep;
                float4 v1 = *(const float4*)(ep + 4);
                bh8 tv;
                tv[0] = (short)f2bf(v0.x); tv[1] = (short)f2bf(v0.y);
                tv[2] = (short)f2bf(v0.z); tv[3] = (short)f2bf(v0.w);
                tv[4] = (short)f2bf(v1.x); tv[5] = (short)f2bf(v1.y);
                tv[6] = (short)f2bf(v1.z); tv[7] = (short)f2bf(v1.w);
                a = tv;
            }
            const unsigned short* wrow = we + ((size_t)(kt * 4 + q) * 32 + lm) * 8;
            bh8 b0 = *(const bh8*)(wrow);
            bh8 b1 = *(const bh8*)(wrow + 16 * 8);
            acc[0] = __builtin_amdgcn_mfma_f32_16x16x32_bf16(a, b0, acc[0], 0, 0, 0);
            acc[1] = __builtin_amdgcn_mfma_f32_16x16x32_bf16(a, b1, acc[1], 0, 0, 0);
        }

        // edge part of agg1 row: mean over the 16 rows of this segment
#pragma unroll
        for (int nt = 0; nt < 2; ++nt) {
            float ps = 0.f;
#pragma unroll
            for (int rr = 0; rr < 4; ++rr) ps += fmaxf(acc[nt][rr], 0.f);
            ps += __shfl_xor(ps, 16);
            ps += __shfl_xor(ps, 32);               // sum over quads -> full column sum
            if (l < 16)
                As2[w][256 + nt * 16 + lm] = f2bf(ps * inv);
        }

        // f0 row (dims 2l, 2l+1) and f1 mean
        {
            const int seg = m0 >> 4;
            unsigned int f0u = ((const unsigned int*)a0p)[l];
            ((unsigned int*)&As2[w][0])[l] = f0u;

            const unsigned short* fr = f1base + (size_t)seg * 16 * 128;
            float s0 = 0.f, s1 = 0.f;
#pragma unroll
            for (int j = 0; j < S; ++j) {
                unsigned int u = ((const unsigned int*)(fr + j * 128))[l];
                s0 += bf2f((unsigned short)(u & 0xFFFF));
                s1 += bf2f((unsigned short)(u >> 16));
            }
            ((unsigned int*)&As2[w][0])[64 + l] =
                (unsigned int)f2bf(s0 * inv) | ((unsigned int)f2bf(s1 * inv) << 16);
        }
        __syncthreads();

        // ---- L1 GEMM: 4 valid rows, 8 n-tiles over 4 waves -> fembs[mp] ----
        const unsigned short* wb1 = WT0 + ((size_t)mp * 2 + 1) * WSTRIDE;
        f4 acc2[2];
        acc2[0] = (f4){0.f, 0.f, 0.f, 0.f};
        acc2[1] = (f4){0.f, 0.f, 0.f, 0.f};

#pragma unroll
        for (int kt = 0; kt < NKT; ++kt) {
            const int k0 = kt * 32 + q * 8;
            bh8 a;
            if (lm < 4) a = *(const bh8*)&As2[lm][k0];
            else        a = (bh8){0, 0, 0, 0, 0, 0, 0, 0};
            const unsigned short* wrow = wb1 + ((size_t)(kt * 4 + q) * 128 + lm) * 8;
#pragma unroll
            for (int ntl = 0; ntl < 2; ++ntl) {
                bh8 bf = *(const bh8*)(wrow + (w * 2 + ntl) * 16 * 8);
                acc2[ntl] = __builtin_amdgcn_mfma_f32_16x16x32_bf16(a, bf, acc2[ntl], 0, 0, 0);
            }
        }
        if (q == 0) {                               // rows 0-3 live in quad 0, reg rr
#pragma unroll
            for (int ntl = 0; ntl < 2; ++ntl)
#pragma unroll
                for (int rr = 0; rr < 4; ++rr)
                    fembs[mp][rr][(w * 2 + ntl) * 16 + lm] = fmaxf(acc2[ntl][rr], 0.f);
        }
        __syncthreads();                            // As2 reused next mp; fembs complete
    }

    // ---- finalize: 4 rows x 8 threads (threads 0..31), 16 dims each ----
    if (threadIdx.x < 32) {
        const int row = threadIdx.x >> 3;           // local row 0..3
        const int j = threadIdx.x & 7;
        const int d0 = j * 16;

        float sc[NMP];
#pragma unroll
        for (int mp = 0; mp < NMP; ++mp) {
            float p = 0.f;
#pragma unroll
            for (int d = 0; d < 16; ++d) p += fembs[mp][row][d0 + d] * attn[d0 + d];
            p += __shfl_xor(p, 1); p += __shfl_xor(p, 2); p += __shfl_xor(p, 4);
            sc[mp] = tanhf(p);
        }
        float mx = fmaxf(sc[0], fmaxf(sc[1], sc[2]));
        float e0 = expf(sc[0] - mx), e1 = expf(sc[1] - mx), e2 = expf(sc[2] - mx);
        float isum = 1.f / (e0 + e1 + e2);
        float b0 = e0 * isum, b1 = e1 * isum, b2 = e2 * isum;

        float emb[16];
        float nn = 0.f;
#pragma unroll
        for (int d = 0; d < 16; ++d) {
            float vv = b0 * fembs[0][row][d0 + d] + b1 * fembs[1][row][d0 + d]
                     + b2 * fembs[2][row][d0 + d];
            emb[d] = vv;
            nn += vv * vv;
        }
        nn += __shfl_xor(nn, 1); nn += __shfl_xor(nn, 2); nn += __shfl_xor(nn, 4);
        float innorm = 1.f / fmaxf(sqrtf(nn), 1e-12f);
#pragma unroll
        for (int d = 0; d < 16; ++d) emb[d] *= innorm;

        const int grow = blockIdx.x * 4 + row;
#pragma unroll
        for (int cc = 0; cc < NC; ++cc) {
            float p = 0.f;
#pragma unroll
            for (int d = 0; d < 16; ++d) p += emb[d] * fcw[(d0 + d) * NC + cc];
            p += __shfl_xor(p, 1); p += __shfl_xor(p, 2); p += __shfl_xor(p, 4);
            if (j == cc) out[(size_t)grow * NC + cc] = p + fcb[cc];
        }
    }
}

extern "C" void kernel_launch(void* const* d_in, const int* in_sizes, int n_in,
                              void* d_out, int out_size, void* d_ws, size_t ws_size,
                              hipStream_t stream) {
    const int* ids        = (const int*)d_in[0];
    const float* feats    = (const float*)d_in[1];
    const float* edge_emb = (const float*)d_in[2];
    const int* adjn       = (const int*)d_in[3];
    const int* adje       = (const int*)d_in[4];
    const float* Ws       = (const float*)d_in[5];
    const float* Wn       = (const float*)d_in[6];
    const float* We       = (const float*)d_in[7];
    const float* attn     = (const float*)d_in[8];
    const float* fcw      = (const float*)d_in[9];
    const float* fcb      = (const float*)d_in[10];
    float* out = (float*)d_out;

    // workspace layout (~27 MB; all regions fully written before read each call)
    char* p = (char*)d_ws;
    unsigned short* WT0 = (unsigned short*)p; p += (size_t)6 * WSTRIDE * 2;
    unsigned short* WTe = (unsigned short*)p; p += (size_t)3 * WESTRIDE * 2;
    unsigned short* fb  = (unsigned short*)p; p += (size_t)NNODES * 128 * 2;
    int* gx   = (int*)p;                      p += (size_t)3 * RPM * 4;
    int* eid1 = (int*)p;                      p += (size_t)3 * 16384 * 4;
    unsigned short* fout = (unsigned short*)p; p += (size_t)3 * RPM * 128 * 2;

    convsamp_k<<<TOT_TASKS / 256, 256, 0, stream>>>(feats, Ws, Wn, We, ids, adjn, adje,
                                                    fb, WT0, WTe, gx, eid1);
    aggfeat_k<<<dim3(RPM / 32, 3), 512, 0, stream>>>(fb, edge_emb, adjn, adje, gx, eid1,
                                                     WT0, fout);
    edgeaggfin_k<<<256, 256, 0, stream>>>(fout, edge_emb, eid1, WTe, WT0,
                                          attn, fcw, fcb, out);
}

// Round 9
// 224.540 us; speedup vs baseline: 2.2127x; 1.0216x over previous
//
#include <hip/hip_runtime.h>

// Problem constants
#define NNODES  50000
#define D       128
#define E       32
#define NMP     3
#define DEG     32
#define NEDGE   200000
#define B       1024
#define NC      8
#define S       16

#define RPM      17408   // rows per mp in L0 row space (16384 level-1 + 1024 level-0)
#define NKT      9       // K tiles of 32 (K=288)
#define WSTRIDE  36864   // ushorts per (mp,lay) feat-weight block: 9*4*128*8
#define WESTRIDE 9216    // ushorts per mp edge-weight block: 9*4*32*8

#define CONV_TASKS (1600000 + 6 * WSTRIDE + 3 * WESTRIDE)   // 1,848,832
#define TOT_TASKS  (CONV_TASKS + 3 * RPM)                    // 1,901,056 = 7426*256

typedef float f4 __attribute__((ext_vector_type(4)));
typedef float f2 __attribute__((ext_vector_type(2)));
typedef short bh8 __attribute__((ext_vector_type(8)));   // 8 bf16 in 4 VGPRs
typedef unsigned int uv4 __attribute__((ext_vector_type(4)));
typedef unsigned int uv2 __attribute__((ext_vector_type(2)));
typedef int iv4 __attribute__((ext_vector_type(4)));
typedef int iv2 __attribute__((ext_vector_type(2)));

static __device__ __forceinline__ unsigned short f2bf(float f) {
    unsigned int u = __float_as_uint(f);
    u = u + 0x7FFFu + ((u >> 16) & 1u);   // RN-even
    return (unsigned short)(u >> 16);
}
static __device__ __forceinline__ float bf2f(unsigned short h) {
    return __uint_as_float(((unsigned int)h) << 16);
}

// ---------- fused one-shot conversion + level-1 sampling ----------
// Also builds the fp8-e4m3 shadow feature table f8b (6.4 MB) used by the
// level-1 neighbor gathers (halves the dominant gather traffic).
__global__ __launch_bounds__(256) void convsamp_k(
    const float* __restrict__ feats, const float* __restrict__ Ws,
    const float* __restrict__ Wn, const float* __restrict__ We,
    const int* __restrict__ ids, const int* __restrict__ adjn,
    const int* __restrict__ adje,
    unsigned short* __restrict__ fb, unsigned char* __restrict__ f8b,
    unsigned short* __restrict__ WT0,
    unsigned short* __restrict__ WTe, int* __restrict__ gx, int* __restrict__ eid1)
{
    int i = blockIdx.x * 256 + threadIdx.x;
    if (i < 1600000) {                          // feats: 50000*128/4 float4 tasks
        float4 v = ((const float4*)feats)[i];
        unsigned int p0 = (unsigned int)f2bf(v.x) | ((unsigned int)f2bf(v.y) << 16);
        unsigned int p1 = (unsigned int)f2bf(v.z) | ((unsigned int)f2bf(v.w) << 16);
        ((uint2*)fb)[i] = make_uint2(p0, p1);
        unsigned int u8 = __builtin_amdgcn_cvt_pk_fp8_f32(v.x, v.y, 0, false);
        u8 = __builtin_amdgcn_cvt_pk_fp8_f32(v.z, v.w, u8, true);
        ((unsigned int*)f8b)[i] = u8;
    } else if (i < 1600000 + 6 * WSTRIDE) {     // feat weights: [mp][lay] K=288 (Ws||Wn), N=128
        int i2 = i - 1600000;
        int ml = i2 / WSTRIDE, e = i2 % WSTRIDE;
        int j = e & 7, t1 = e >> 3;
        int n = t1 & 127, t2 = t1 >> 7;
        int q = t2 & 3, kt = t2 >> 2;
        int k = kt * 32 + q * 8 + j;
        float v = (k < 128) ? Ws[((size_t)ml * 128 + k) * 128 + n]
                            : Wn[((size_t)ml * 160 + (k - 128)) * 128 + n];
        WT0[(size_t)ml * WSTRIDE + e] = f2bf(v);
    } else if (i < CONV_TASKS) {                // edge weights: [mp][lay0] K=288,N=32
        int i3 = i - 1600000 - 6 * WSTRIDE;
        int mp = i3 / WESTRIDE, e = i3 % WESTRIDE;
        int j = e & 7, t1 = e >> 3;
        int n = t1 & 31, t2 = t1 >> 5;
        int q = t2 & 3, kt = t2 >> 2;
        int k = kt * 32 + q * 8 + j;
        float v = We[(((size_t)mp * 2) * 288 + k) * 32 + n];
        WTe[(size_t)mp * WESTRIDE + e] = f2bf(v);
    } else if (i < TOT_TASKS) {                 // sampling: 3*RPM tasks
        int i4 = i - CONV_TASKS;
        int mp = i4 / RPM, r = i4 % RPM;
        if (r < 16384) {
            int node = ids[r >> 4];
            gx[mp * RPM + r]     = adjn[((size_t)mp * NNODES + node) * DEG + (r & 15)];
            eid1[mp * 16384 + r] = adje[((size_t)mp * NNODES + node) * DEG + (r & 15)];
        } else {
            gx[mp * RPM + r] = ids[r - 16384];
        }
    }
}

// ---------- fused gather-mean + layer-0 MFMA GEMM -> fout [mp][RPM][128] bf16 ----------
// R2 geometry (best measured 58us). Level-1 blocks (94% of gather traffic)
// gather neighbor rows from the fp8 table: 128B/row instead of 256B, decoded
// with v_cvt_pk_f32_fp8 before the f32 mean. Level-0 blocks (direct output
// path, 6% of traffic) keep full bf16 gathers. Service-rate-bound diagnosis:
// 7 issue-structure variants all 58-67us at FETCH 146MB -> only bytes help.
__global__ __launch_bounds__(256, 3) void aggfeat_k(
    const unsigned short* __restrict__ fb, const unsigned char* __restrict__ f8b,
    const float* __restrict__ edge_emb,
    const int* __restrict__ adjn, const int* __restrict__ adje,
    const int* __restrict__ gx, const int* __restrict__ eid1,
    const unsigned short* __restrict__ WT0,
    unsigned short* __restrict__ fout)
{
    __shared__ unsigned short Asm[16][136];   // self feats (128 used)
    __shared__ unsigned short Nsm[16][168];   // nin rows (160 used)
    const int mp = blockIdx.y;
    const int w = threadIdx.x >> 6, l = threadIdx.x & 63;
    const int r0 = blockIdx.x * 16;
    const unsigned int* fb32 = (const unsigned int*)fb;
    const float* ee = edge_emb + (size_t)mp * NEDGE * E;
    const float inv = 1.0f / (float)S;
    const int d8 = l & 7;                     // edge gather: 8 lanes per edge row

    if (r0 < 16384) {
        // ================= level-1 blocks: fp8 neighbor gathers =================
        const int h = l >> 3, c8 = l & 7;     // h: neighbor sub-idx, c8: 16-dim slot
        iv4 srcv = *(const iv4*)(gx + mp * RPM + r0 + w * 4);

        int nid[4][2]; iv2 eIdx[4]; unsigned int selfu[4];
#pragma unroll
        for (int rr = 0; rr < 4; ++rr) {
            const int src = srcv[rr];
            const int* nb = adjn + ((size_t)mp * NNODES + src) * DEG;
            nid[rr][0] = nb[h];
            nid[rr][1] = nb[8 + h];
            eIdx[rr]  = *(const iv2*)(adje + ((size_t)mp * NNODES + src) * DEG + 2 * (l >> 3));
            selfu[rr] = fb32[(size_t)src * 64 + l];
        }

        // issue ALL gathers (8 fp8-row loads + 8 edge loads) before the fence
        uv4 gF[4][2];
        f4  gE[4][2];
#pragma unroll
        for (int rr = 0; rr < 4; ++rr) {
            gF[rr][0] = *(const uv4*)(f8b + (size_t)nid[rr][0] * 128 + c8 * 16);
            gF[rr][1] = *(const uv4*)(f8b + (size_t)nid[rr][1] * 128 + c8 * 16);
            gE[rr][0] = *(const f4*)(ee + (size_t)eIdx[rr][0] * E + d8 * 4);
            gE[rr][1] = *(const f4*)(ee + (size_t)eIdx[rr][1] * E + d8 * 4);
        }
        asm volatile("" ::: "memory");   // hard fence: no load may sink past here

#pragma unroll
        for (int rr = 0; rr < 4; ++rr) {
            const int lr = w * 4 + rr;
            float acc[16];
#pragma unroll
            for (int d = 0; d < 16; ++d) acc[d] = 0.f;
#pragma unroll
            for (int i = 0; i < 2; ++i)
#pragma unroll
                for (int d = 0; d < 4; ++d) {
                    unsigned int u = gF[rr][i][d];
                    f2 p0 = __builtin_amdgcn_cvt_pk_f32_fp8(u, false);
                    f2 p1 = __builtin_amdgcn_cvt_pk_f32_fp8(u, true);
                    acc[4 * d + 0] += p0[0];
                    acc[4 * d + 1] += p0[1];
                    acc[4 * d + 2] += p1[0];
                    acc[4 * d + 3] += p1[1];
                }
            // reduce across the 8 neighbor groups (stride 8,16,32)
#pragma unroll
            for (int d = 0; d < 16; ++d) {
                acc[d] += __shfl_xor(acc[d], 8);
                acc[d] += __shfl_xor(acc[d], 16);
                acc[d] += __shfl_xor(acc[d], 32);
            }
            float fe[4];
#pragma unroll
            for (int qq = 0; qq < 4; ++qq) {
                fe[qq] = gE[rr][0][qq] + gE[rr][1][qq];
                fe[qq] += __shfl_xor(fe[qq], 8);
                fe[qq] += __shfl_xor(fe[qq], 16);
                fe[qq] += __shfl_xor(fe[qq], 32);
            }

            ((unsigned int*)&Asm[lr][0])[l] = selfu[rr];
            if (h == 0) {                      // lanes 0..7: dims c8*16 .. c8*16+15
                uv4 o1, o2;
#pragma unroll
                for (int k = 0; k < 4; ++k) {
                    o1[k] = (unsigned int)f2bf(acc[2 * k] * inv)
                          | ((unsigned int)f2bf(acc[2 * k + 1] * inv) << 16);
                    o2[k] = (unsigned int)f2bf(acc[8 + 2 * k] * inv)
                          | ((unsigned int)f2bf(acc[8 + 2 * k + 1] * inv) << 16);
                }
                *(uv4*)&Nsm[lr][c8 * 16]     = o1;
                *(uv4*)&Nsm[lr][c8 * 16 + 8] = o2;
            }
            if (l < 8) {
                uv2 o;
                o[0] = (unsigned int)f2bf(fe[0] * inv) | ((unsigned int)f2bf(fe[1] * inv) << 16);
                o[1] = (unsigned int)f2bf(fe[2] * inv) | ((unsigned int)f2bf(fe[3] * inv) << 16);
                *(uv2*)&Nsm[lr][128 + d8 * 4] = o;
            }
        }
    } else {
        // ================= level-0 blocks: bf16 neighbor gathers (R2 path) ======
        const int g = l >> 4, c = l & 15;
        iv4 srcv = *(const iv4*)(gx + mp * RPM + r0 + w * 4);

        iv4 nIdx[4]; iv2 eIdx[4]; unsigned int selfu[4];
#pragma unroll
        for (int rr = 0; rr < 4; ++rr) {
            const int src = srcv[rr];
            nIdx[rr]  = *(const iv4*)(adjn + ((size_t)mp * NNODES + src) * DEG + 4 * g);
            eIdx[rr]  = *(const iv2*)(adje + ((size_t)mp * NNODES + src) * DEG + 2 * (l >> 3));
            selfu[rr] = fb32[(size_t)src * 64 + l];
        }

        uv4 gN[4][4];
        f4  gE[4][2];
#pragma unroll
        for (int rr = 0; rr < 4; ++rr) {
#pragma unroll
            for (int p = 0; p < 4; ++p)
                gN[rr][p] = *(const uv4*)(fb32 + (size_t)nIdx[rr][p] * 64 + c * 4);
            gE[rr][0] = *(const f4*)(ee + (size_t)eIdx[rr][0] * E + d8 * 4);
            gE[rr][1] = *(const f4*)(ee + (size_t)eIdx[rr][1] * E + d8 * 4);
        }
        asm volatile("" ::: "memory");

#pragma unroll
        for (int rr = 0; rr < 4; ++rr) {
            const int lr = w * 4 + rr;
            float acc[8];
#pragma unroll
            for (int d = 0; d < 8; ++d) acc[d] = 0.f;
#pragma unroll
            for (int p = 0; p < 4; ++p)
#pragma unroll
                for (int qq = 0; qq < 4; ++qq) {
                    unsigned int u = gN[rr][p][qq];
                    acc[2 * qq]     += __uint_as_float(u << 16);
                    acc[2 * qq + 1] += __uint_as_float(u & 0xffff0000u);
                }
#pragma unroll
            for (int d = 0; d < 8; ++d) {
                acc[d] += __shfl_xor(acc[d], 16);
                acc[d] += __shfl_xor(acc[d], 32);
            }
            float fe[4];
#pragma unroll
            for (int qq = 0; qq < 4; ++qq) {
                fe[qq] = gE[rr][0][qq] + gE[rr][1][qq];
                fe[qq] += __shfl_xor(fe[qq], 8);
                fe[qq] += __shfl_xor(fe[qq], 16);
                fe[qq] += __shfl_xor(fe[qq], 32);
            }

            ((unsigned int*)&Asm[lr][0])[l] = selfu[rr];
            if (g == 0) {
                uv4 o;
#pragma unroll
                for (int qq = 0; qq < 4; ++qq)
                    o[qq] = (unsigned int)f2bf(acc[2 * qq] * inv)
                          | ((unsigned int)f2bf(acc[2 * qq + 1] * inv) << 16);
                *(uv4*)&Nsm[lr][c * 8] = o;
            }
            if (l < 8) {
                uv2 o;
                o[0] = (unsigned int)f2bf(fe[0] * inv) | ((unsigned int)f2bf(fe[1] * inv) << 16);
                o[1] = (unsigned int)f2bf(fe[2] * inv) | ((unsigned int)f2bf(fe[3] * inv) << 16);
                *(uv2*)&Nsm[lr][128 + d8 * 4] = o;
            }
        }
    }
    __syncthreads();

    // ---- phase B: wave w computes n-tiles {2w, 2w+1} of the single m-tile ----
    const int q = l >> 4, lm = l & 15;
    const unsigned short* wb = WT0 + (size_t)mp * 2 * WSTRIDE;   // layer 0

    f4 acc[2];
    acc[0] = (f4){0.f, 0.f, 0.f, 0.f};
    acc[1] = (f4){0.f, 0.f, 0.f, 0.f};

#pragma unroll
    for (int kt = 0; kt < NKT; ++kt) {
        const int k0 = kt * 32 + q * 8;
        bh8 a = (k0 < 128) ? *(const bh8*)&Asm[lm][k0]
                           : *(const bh8*)&Nsm[lm][k0 - 128];
        const unsigned short* wrow = wb + ((size_t)(kt * 4 + q) * 128 + lm) * 8;
#pragma unroll
        for (int ntl = 0; ntl < 2; ++ntl) {
            bh8 bf = *(const bh8*)(wrow + (w * 2 + ntl) * 16 * 8);
            acc[ntl] = __builtin_amdgcn_mfma_f32_16x16x32_bf16(a, bf, acc[ntl], 0, 0, 0);
        }
    }

#pragma unroll
    for (int ntl = 0; ntl < 2; ++ntl)
#pragma unroll
        for (int rr = 0; rr < 4; ++rr) {
            int row = r0 + q * 4 + rr;             // C/D: col=lane&15, row=quad*4+reg
            int col = (w * 2 + ntl) * 16 + lm;
            fout[((size_t)mp * RPM + row) * 128 + col] = f2bf(fmaxf(acc[ntl][rr], 0.f));
        }
}

// ---------- fully fused tail: edge GEMM + L1 mean + L1 GEMM (all 3 mps)
//            + attention + softmax + normalize + fc -> out ----------
__global__ __launch_bounds__(256) void edgeaggfin_k(
    const unsigned short* __restrict__ fout, const float* __restrict__ edge_emb,
    const int* __restrict__ eid1, const unsigned short* __restrict__ WTe,
    const unsigned short* __restrict__ WT0,
    const float* __restrict__ attn, const float* __restrict__ fcw,
    const float* __restrict__ fcb, float* __restrict__ out)
{
    __shared__ unsigned short As2[4][304];      // 288 used; 608B rows (16B-aligned)
    __shared__ float fembs[NMP][4][128];        // relu(L1 GEMM) for this block's 4 rows
    const int w = threadIdx.x >> 6, l = threadIdx.x & 63;
    const int q = l >> 4, lm = l & 15;
    const float inv = 1.0f / (float)S;

    for (int mp = 0; mp < NMP; ++mp) {
        const int m0 = (blockIdx.x * 4 + w) * 16;          // wave: 1 m-tile = 1 segment
        const unsigned short* we = WTe + (size_t)mp * WESTRIDE;
        const unsigned short* f1base = fout + (size_t)mp * RPM * 128;
        const unsigned short* f0base = fout + ((size_t)mp * RPM + 16384) * 128;
        const float* ee = edge_emb + (size_t)mp * NEDGE * E;

        const int row = m0 + lm;
        const unsigned short* a1p = f1base + (size_t)row * 128;
        const unsigned short* a0p = f0base + (size_t)(row >> 4) * 128;
        const int eidL = eid1[mp * 16384 + row];

        f4 acc[2];
        acc[0] = (f4){0.f, 0.f, 0.f, 0.f};
        acc[1] = (f4){0.f, 0.f, 0.f, 0.f};

#pragma unroll
        for (int kt = 0; kt < NKT; ++kt) {
            const int k0 = kt * 32 + q * 8;
            bh8 a;
            if (kt < 4) {
                a = *(const bh8*)(a0p + k0);
            } else if (kt < 8) {
                a = *(const bh8*)(a1p + (k0 - 128));
            } else {
                const float* ep = ee + (size_t)eidL * E + q * 8;
                float4 v0 = *(const float4*)ep;
                float4 v1 = *(const float4*)(ep + 4);
                bh8 tv;
                tv[0] = (short)f2bf(v0.x); tv[1] = (short)f2bf(v0.y);
                tv[2] = (short)f2bf(v0.z); tv[3] = (short)f2bf(v0.w);
                tv[4] = (short)f2bf(v1.x); tv[5] = (short)f2bf(v1.y);
                tv[6] = (short)f2bf(v1.z); tv[7] = (short)f2bf(v1.w);
                a = tv;
            }
            const unsigned short* wrow = we + ((size_t)(kt * 4 + q) * 32 + lm) * 8;
            bh8 b0 = *(const bh8*)(wrow);
            bh8 b1 = *(const bh8*)(wrow + 16 * 8);
            acc[0] = __builtin_amdgcn_mfma_f32_16x16x32_bf16(a, b0, acc[0], 0, 0, 0);
            acc[1] = __builtin_amdgcn_mfma_f32_16x16x32_bf16(a, b1, acc[1], 0, 0, 0);
        }

        // edge part of agg1 row: mean over the 16 rows of this segment
#pragma unroll
        for (int nt = 0; nt < 2; ++nt) {
            float ps = 0.f;
#pragma unroll
            for (int rr = 0; rr < 4; ++rr) ps += fmaxf(acc[nt][rr], 0.f);
            ps += __shfl_xor(ps, 16);
            ps += __shfl_xor(ps, 32);               // sum over quads -> full column sum
            if (l < 16)
                As2[w][256 + nt * 16 + lm] = f2bf(ps * inv);
        }

        // f0 row (dims 2l, 2l+1) and f1 mean
        {
            const int seg = m0 >> 4;
            unsigned int f0u = ((const unsigned int*)a0p)[l];
            ((unsigned int*)&As2[w][0])[l] = f0u;

            const unsigned short* fr = f1base + (size_t)seg * 16 * 128;
            float s0 = 0.f, s1 = 0.f;
#pragma unroll
            for (int j = 0; j < S; ++j) {
                unsigned int u = ((const unsigned int*)(fr + j * 128))[l];
                s0 += bf2f((unsigned short)(u & 0xFFFF));
                s1 += bf2f((unsigned short)(u >> 16));
            }
            ((unsigned int*)&As2[w][0])[64 + l] =
                (unsigned int)f2bf(s0 * inv) | ((unsigned int)f2bf(s1 * inv) << 16);
        }
        __syncthreads();

        // ---- L1 GEMM: 4 valid rows, 8 n-tiles over 4 waves -> fembs[mp] ----
        const unsigned short* wb1 = WT0 + ((size_t)mp * 2 + 1) * WSTRIDE;
        f4 acc2[2];
        acc2[0] = (f4){0.f, 0.f, 0.f, 0.f};
        acc2[1] = (f4){0.f, 0.f, 0.f, 0.f};

#pragma unroll
        for (int kt = 0; kt < NKT; ++kt) {
            const int k0 = kt * 32 + q * 8;
            bh8 a;
            if (lm < 4) a = *(const bh8*)&As2[lm][k0];
            else        a = (bh8){0, 0, 0, 0, 0, 0, 0, 0};
            const unsigned short* wrow = wb1 + ((size_t)(kt * 4 + q) * 128 + lm) * 8;
#pragma unroll
            for (int ntl = 0; ntl < 2; ++ntl) {
                bh8 bf = *(const bh8*)(wrow + (w * 2 + ntl) * 16 * 8);
                acc2[ntl] = __builtin_amdgcn_mfma_f32_16x16x32_bf16(a, bf, acc2[ntl], 0, 0, 0);
            }
        }
        if (q == 0) {                               // rows 0-3 live in quad 0, reg rr
#pragma unroll
            for (int ntl = 0; ntl < 2; ++ntl)
#pragma unroll
                for (int rr = 0; rr < 4; ++rr)
                    fembs[mp][rr][(w * 2 + ntl) * 16 + lm] = fmaxf(acc2[ntl][rr], 0.f);
        }
        __syncthreads();                            // As2 reused next mp; fembs complete
    }

    // ---- finalize: 4 rows x 8 threads (threads 0..31), 16 dims each ----
    if (threadIdx.x < 32) {
        const int row = threadIdx.x >> 3;           // local row 0..3
        const int j = threadIdx.x & 7;
        const int d0 = j * 16;

        float sc[NMP];
#pragma unroll
        for (int mp = 0; mp < NMP; ++mp) {
            float p = 0.f;
#pragma unroll
            for (int d = 0; d < 16; ++d) p += fembs[mp][row][d0 + d] * attn[d0 + d];
            p += __shfl_xor(p, 1); p += __shfl_xor(p, 2); p += __shfl_xor(p, 4);
            sc[mp] = tanhf(p);
        }
        float mx = fmaxf(sc[0], fmaxf(sc[1], sc[2]));
        float e0 = expf(sc[0] - mx), e1 = expf(sc[1] - mx), e2 = expf(sc[2] - mx);
        float isum = 1.f / (e0 + e1 + e2);
        float b0 = e0 * isum, b1 = e1 * isum, b2 = e2 * isum;

        float emb[16];
        float nn = 0.f;
#pragma unroll
        for (int d = 0; d < 16; ++d) {
            float vv = b0 * fembs[0][row][d0 + d] + b1 * fembs[1][row][d0 + d]
                     + b2 * fembs[2][row][d0 + d];
            emb[d] = vv;
            nn += vv * vv;
        }
        nn += __shfl_xor(nn, 1); nn += __shfl_xor(nn, 2); nn += __shfl_xor(nn, 4);
        float innorm = 1.f / fmaxf(sqrtf(nn), 1e-12f);
#pragma unroll
        for (int d = 0; d < 16; ++d) emb[d] *= innorm;

        const int grow = blockIdx.x * 4 + row;
#pragma unroll
        for (int cc = 0; cc < NC; ++cc) {
            float p = 0.f;
#pragma unroll
            for (int d = 0; d < 16; ++d) p += emb[d] * fcw[(d0 + d) * NC + cc];
            p += __shfl_xor(p, 1); p += __shfl_xor(p, 2); p += __shfl_xor(p, 4);
            if (j == cc) out[(size_t)grow * NC + cc] = p + fcb[cc];
        }
    }
}

extern "C" void kernel_launch(void* const* d_in, const int* in_sizes, int n_in,
                              void* d_out, int out_size, void* d_ws, size_t ws_size,
                              hipStream_t stream) {
    const int* ids        = (const int*)d_in[0];
    const float* feats    = (const float*)d_in[1];
    const float* edge_emb = (const float*)d_in[2];
    const int* adjn       = (const int*)d_in[3];
    const int* adje       = (const int*)d_in[4];
    const float* Ws       = (const float*)d_in[5];
    const float* Wn       = (const float*)d_in[6];
    const float* We       = (const float*)d_in[7];
    const float* attn     = (const float*)d_in[8];
    const float* fcw      = (const float*)d_in[9];
    const float* fcb      = (const float*)d_in[10];
    float* out = (float*)d_out;

    // workspace layout (~33.5 MB; all regions fully written before read each call)
    char* p = (char*)d_ws;
    unsigned short* WT0 = (unsigned short*)p; p += (size_t)6 * WSTRIDE * 2;
    unsigned short* WTe = (unsigned short*)p; p += (size_t)3 * WESTRIDE * 2;
    unsigned short* fb  = (unsigned short*)p; p += (size_t)NNODES * 128 * 2;
    unsigned char*  f8b = (unsigned char*)p;  p += (size_t)NNODES * 128;
    int* gx   = (int*)p;                      p += (size_t)3 * RPM * 4;
    int* eid1 = (int*)p;                      p += (size_t)3 * 16384 * 4;
    unsigned short* fout = (unsigned short*)p; p += (size_t)3 * RPM * 128 * 2;

    convsamp_k<<<TOT_TASKS / 256, 256, 0, stream>>>(feats, Ws, Wn, We, ids, adjn, adje,
                                                    fb, f8b, WT0, WTe, gx, eid1);
    aggfeat_k<<<dim3(RPM / 16, 3), 256, 0, stream>>>(fb, f8b, edge_emb, adjn, adje,
                                                     gx, eid1, WT0, fout);
    edgeaggfin_k<<<256, 256, 0, stream>>>(fout, edge_emb, eid1, WTe, WT0,
                                          attn, fcw, fcb, out);
}